// Round 1
// baseline (1955.036 us; speedup 1.0000x reference)
//
#include <hip/hip_runtime.h>
#include <math.h>

#define N_NODES 100000
#define E_EDGES 1600000
#define ET (E_EDGES + N_NODES)
#define F_IN 128
#define D_DIM 16
#define H_HEADS 8
#define HD 128
#define NEG_SLOPE 0.2f

// ---------------------------------------------------------------------------
// Embedding: h0[n, 0..15] = x[n, :] @ W_emb + b_emb
// Block 256: 16 nodes per iter, thread t -> (node t>>4, channel t&15)
// ---------------------------------------------------------------------------
__global__ __launch_bounds__(256) void embed_kernel(
        const float* __restrict__ x, const float* __restrict__ W,
        const float* __restrict__ b, float* __restrict__ h0) {
    __shared__ float Ws[F_IN * D_DIM];   // 8 KB
    __shared__ float bs[D_DIM];
    __shared__ float xs[16][F_IN + 1];   // +1 pad: avoid 4-way bank conflict
    int t = threadIdx.x;
    for (int i = t; i < F_IN * D_DIM; i += 256) Ws[i] = W[i];
    if (t < D_DIM) bs[t] = b[t];
    __syncthreads();
    for (int base = blockIdx.x * 16; base < N_NODES; base += gridDim.x * 16) {
        int cnt = min(16, N_NODES - base);
        __syncthreads();
        for (int i = t; i < cnt * F_IN; i += 256) {
            int nn = i >> 7, k = i & 127;
            xs[nn][k] = x[(size_t)(base + nn) * F_IN + k];
        }
        __syncthreads();
        int nn = t >> 4, c = t & 15;
        if (nn < cnt) {
            float a0 = 0.f, a1 = 0.f, a2 = 0.f, a3 = 0.f;
            #pragma unroll
            for (int k = 0; k < F_IN; k += 4) {
                a0 += xs[nn][k + 0] * Ws[(k + 0) * D_DIM + c];
                a1 += xs[nn][k + 1] * Ws[(k + 1) * D_DIM + c];
                a2 += xs[nn][k + 2] * Ws[(k + 2) * D_DIM + c];
                a3 += xs[nn][k + 3] * Ws[(k + 3) * D_DIM + c];
            }
            h0[(size_t)(base + nn) * D_DIM + c] = (a0 + a1) + (a2 + a3) + bs[c];
        }
    }
}

// ---------------------------------------------------------------------------
// Node transform: g[n, c] = sum_k h[n, k] * W[k, c]   (c = head*16 + d)
// a_src[n, head] = sum_d g[n,head,d]*att_s[head,d]; same for a_dst.
// Block 256 = 2 nodes (128 channels each). W staged in LDS.
// h row read via wave-uniform (scalar) loads.
// ---------------------------------------------------------------------------
template<int K>
__global__ __launch_bounds__(256) void transform_kernel(
        const float* __restrict__ h, const float* __restrict__ W,
        const float* __restrict__ att_s, const float* __restrict__ att_d,
        float* __restrict__ g, float* __restrict__ a_src, float* __restrict__ a_dst) {
    __shared__ float Ws[K * HD];         // K=128 -> 64 KB, K=16 -> 8 KB
    int t = threadIdx.x;
    for (int i = t; i < K * HD; i += 256) Ws[i] = W[i];
    __syncthreads();
    int half = t >> 7;      // which node in the pair
    int c = t & 127;        // output channel
    float asc = att_s[c], adc = att_d[c];
    for (int base = blockIdx.x * 2; base < N_NODES; base += gridDim.x * 2) {
        int n = base + half;           // N even -> always valid
        const float* hr = h + (size_t)n * K;
        float a0 = 0.f, a1 = 0.f, a2 = 0.f, a3 = 0.f;
        #pragma unroll
        for (int k = 0; k < K; k += 4) {
            a0 += hr[k + 0] * Ws[(k + 0) * HD + c];
            a1 += hr[k + 1] * Ws[(k + 1) * HD + c];
            a2 += hr[k + 2] * Ws[(k + 2) * HD + c];
            a3 += hr[k + 3] * Ws[(k + 3) * HD + c];
        }
        float acc = (a0 + a1) + (a2 + a3);
        g[(size_t)n * HD + c] = acc;
        float ps = acc * asc, pd = acc * adc;
        #pragma unroll
        for (int m = 1; m < 16; m <<= 1) {
            ps += __shfl_xor(ps, m);
            pd += __shfl_xor(pd, m);
        }
        if ((c & 15) == 0) {
            a_src[(size_t)n * H_HEADS + (c >> 4)] = ps;
            a_dst[(size_t)n * H_HEADS + (c >> 4)] = pd;
        }
    }
}

// ---------------------------------------------------------------------------
// Edge pass 1: denom[dst, h] += exp(leaky_relu(a_src[src,h] + a_dst[dst,h]))
// Thread per (edge, head).
// ---------------------------------------------------------------------------
__global__ __launch_bounds__(256) void edge_denom_kernel(
        const int* __restrict__ ei, const float* __restrict__ a_src,
        const float* __restrict__ a_dst, float* __restrict__ denom) {
    int idx = blockIdx.x * 256 + threadIdx.x;
    if (idx >= ET * H_HEADS) return;
    int e = idx >> 3, hh = idx & 7;
    int s, d;
    if (e < E_EDGES) { s = ei[e]; d = ei[E_EDGES + e]; }
    else             { s = d = e - E_EDGES; }
    float a = a_src[s * 8 + hh] + a_dst[d * 8 + hh];
    float l = (a > 0.f) ? a : NEG_SLOPE * a;
    atomicAdd(&denom[d * 8 + hh], __expf(l));
}

// ---------------------------------------------------------------------------
// Init aggregation buffer to broadcast bias (replaces memset; bias fold).
// ---------------------------------------------------------------------------
__global__ __launch_bounds__(256) void init_bias_kernel(
        float* __restrict__ buf, const float* __restrict__ b) {
    __shared__ float bs[HD];
    if (threadIdx.x < HD) bs[threadIdx.x] = b[threadIdx.x];
    __syncthreads();
    size_t total = (size_t)N_NODES * HD;
    for (size_t i = (size_t)blockIdx.x * 256 + threadIdx.x; i < total;
         i += (size_t)gridDim.x * 256)
        buf[i] = bs[i & 127];
}

// ---------------------------------------------------------------------------
// Edge pass 2: out[dst, c] += g[src, c] * alpha[e, c>>4]
// Wave per edge; lane l handles channels l and l+64 (heads l>>4 and l>>4+4).
// alpha recomputed from L2-resident a_src/a_dst/denom tables.
// ---------------------------------------------------------------------------
__global__ __launch_bounds__(256) void edge_aggr_kernel(
        const int* __restrict__ ei, const float* __restrict__ a_src,
        const float* __restrict__ a_dst, const float* __restrict__ denom,
        const float* __restrict__ g, float* __restrict__ out) {
    int wv = threadIdx.x >> 6, lane = threadIdx.x & 63;
    int e = blockIdx.x * 4 + wv;
    if (e >= ET) return;
    int s, d;
    if (e < E_EDGES) { s = ei[e]; d = ei[E_EDGES + e]; }
    else             { s = d = e - E_EDGES; }
    int h1 = lane >> 4, h2 = h1 + 4;
    float l1 = a_src[s * 8 + h1] + a_dst[d * 8 + h1];
    l1 = (l1 > 0.f) ? l1 : NEG_SLOPE * l1;
    float al1 = __expf(l1) / (denom[d * 8 + h1] + 1e-16f);
    float l2 = a_src[s * 8 + h2] + a_dst[d * 8 + h2];
    l2 = (l2 > 0.f) ? l2 : NEG_SLOPE * l2;
    float al2 = __expf(l2) / (denom[d * 8 + h2] + 1e-16f);
    float g1 = g[(size_t)s * HD + lane];
    float g2 = g[(size_t)s * HD + lane + 64];
    atomicAdd(&out[(size_t)d * HD + lane], g1 * al1);
    atomicAdd(&out[(size_t)d * HD + lane + 64], g2 * al2);
}

// ---------------------------------------------------------------------------
// Heads: causal = h@(Wy1-Wy0) + (by1-by0); prop = sigmoid(relu(h@Wc1+bc1)@Wc2+bc2)
// Wave per node; lane l holds h[l], h[l+64].
// ---------------------------------------------------------------------------
__global__ __launch_bounds__(256) void head_kernel(
        const float* __restrict__ h,
        const float* __restrict__ Wy1, const float* __restrict__ by1,
        const float* __restrict__ Wy0, const float* __restrict__ by0,
        const float* __restrict__ Wc1, const float* __restrict__ bc1,
        const float* __restrict__ Wc2, const float* __restrict__ bc2,
        float* __restrict__ out) {
    int wv = threadIdx.x >> 6, lane = threadIdx.x & 63;
    int n = blockIdx.x * 4 + wv;
    if (n >= N_NODES) return;
    float hA = h[(size_t)n * HD + lane];
    float hB = h[(size_t)n * HD + lane + 64];
    // causal effect
    float p = hA * (Wy1[lane] - Wy0[lane]) + hB * (Wy1[lane + 64] - Wy0[lane + 64]);
    #pragma unroll
    for (int m = 1; m < 64; m <<= 1) p += __shfl_xor(p, m);
    // propensity
    float acc2 = 0.f;
    #pragma unroll
    for (int j = 0; j < D_DIM; ++j) {
        float q = hA * Wc1[lane * D_DIM + j] + hB * Wc1[(lane + 64) * D_DIM + j];
        #pragma unroll
        for (int m = 1; m < 64; m <<= 1) q += __shfl_xor(q, m);
        float z = q + bc1[j];
        z = (z > 0.f) ? z : 0.f;
        acc2 += z * Wc2[j];
    }
    if (lane == 0) {
        out[n] = p + by1[0] - by0[0];
        out[N_NODES + n] = 1.f / (1.f + __expf(-(acc2 + bc2[0])));
    }
}

// ---------------------------------------------------------------------------
extern "C" void kernel_launch(void* const* d_in, const int* in_sizes, int n_in,
                              void* d_out, int out_size, void* d_ws, size_t ws_size,
                              hipStream_t stream) {
    const float* x     = (const float*)d_in[0];
    const int*   ei    = (const int*)  d_in[1];
    const float* W_emb = (const float*)d_in[2];
    const float* b_emb = (const float*)d_in[3];
    const float* W0    = (const float*)d_in[4];
    const float* as0   = (const float*)d_in[5];
    const float* ad0   = (const float*)d_in[6];
    const float* b0    = (const float*)d_in[7];
    const float* W1    = (const float*)d_in[8];
    const float* as1   = (const float*)d_in[9];
    const float* ad1   = (const float*)d_in[10];
    const float* b1    = (const float*)d_in[11];
    const float* Wy1   = (const float*)d_in[12];
    const float* by1   = (const float*)d_in[13];
    const float* Wy0   = (const float*)d_in[14];
    const float* by0   = (const float*)d_in[15];
    const float* Wc1   = (const float*)d_in[16];
    const float* bc1   = (const float*)d_in[17];
    const float* Wc2   = (const float*)d_in[18];
    const float* bc2   = (const float*)d_in[19];
    float* out = (float*)d_out;

    float* ws    = (float*)d_ws;
    float* bufG  = ws;                                   // N*128
    float* bufH  = bufG + (size_t)N_NODES * HD;          // N*128
    float* h0    = bufH + (size_t)N_NODES * HD;          // N*16
    float* a_s   = h0   + (size_t)N_NODES * D_DIM;       // N*8
    float* a_d   = a_s  + (size_t)N_NODES * H_HEADS;     // N*8
    float* denom = a_d  + (size_t)N_NODES * H_HEADS;     // N*8

    int denomBlocks = (ET * H_HEADS + 255) / 256;
    int aggrBlocks  = (ET + 3) / 4;

    // Embedding
    hipLaunchKernelGGL(embed_kernel, dim3(512), dim3(256), 0, stream,
                       x, W_emb, b_emb, h0);

    // ----- GAT layer 0 (K = 16) -----
    hipLaunchKernelGGL(transform_kernel<16>, dim3(1024), dim3(256), 0, stream,
                       h0, W0, as0, ad0, bufG, a_s, a_d);
    hipMemsetAsync(denom, 0, (size_t)N_NODES * H_HEADS * sizeof(float), stream);
    hipLaunchKernelGGL(edge_denom_kernel, dim3(denomBlocks), dim3(256), 0, stream,
                       ei, a_s, a_d, denom);
    hipLaunchKernelGGL(init_bias_kernel, dim3(1024), dim3(256), 0, stream, bufH, b0);
    hipLaunchKernelGGL(edge_aggr_kernel, dim3(aggrBlocks), dim3(256), 0, stream,
                       ei, a_s, a_d, denom, bufG, bufH);

    // ----- GAT layer 1 (K = 128) -----
    hipLaunchKernelGGL(transform_kernel<128>, dim3(1024), dim3(256), 0, stream,
                       bufH, W1, as1, ad1, bufG, a_s, a_d);
    hipMemsetAsync(denom, 0, (size_t)N_NODES * H_HEADS * sizeof(float), stream);
    hipLaunchKernelGGL(edge_denom_kernel, dim3(denomBlocks), dim3(256), 0, stream,
                       ei, a_s, a_d, denom);
    hipLaunchKernelGGL(init_bias_kernel, dim3(1024), dim3(256), 0, stream, bufH, b1);
    hipLaunchKernelGGL(edge_aggr_kernel, dim3(aggrBlocks), dim3(256), 0, stream,
                       ei, a_s, a_d, denom, bufG, bufH);

    // Heads
    hipLaunchKernelGGL(head_kernel, dim3((N_NODES + 3) / 4), dim3(256), 0, stream,
                       bufH, Wy1, by1, Wy0, by0, Wc1, bc1, Wc2, bc2, out);
}

// Round 2
// 1100.411 us; speedup vs baseline: 1.7766x; 1.7766x over previous
//
#include <hip/hip_runtime.h>
#include <math.h>

#define N_NODES 100000
#define E_EDGES 1600000
#define F_IN 128
#define D_DIM 16
#define H_HEADS 8
#define HD 128
#define NEG_SLOPE 0.2f

// ---------------------------------------------------------------------------
// Embedding: h0[n, 0..15] = x[n, :] @ W_emb + b_emb
// ---------------------------------------------------------------------------
__global__ __launch_bounds__(256) void embed_kernel(
        const float* __restrict__ x, const float* __restrict__ W,
        const float* __restrict__ b, float* __restrict__ h0) {
    __shared__ float Ws[F_IN * D_DIM];   // 8 KB
    __shared__ float bs[D_DIM];
    __shared__ float xs[16][F_IN + 1];
    int t = threadIdx.x;
    for (int i = t; i < F_IN * D_DIM; i += 256) Ws[i] = W[i];
    if (t < D_DIM) bs[t] = b[t];
    __syncthreads();
    for (int base = blockIdx.x * 16; base < N_NODES; base += gridDim.x * 16) {
        int cnt = min(16, N_NODES - base);
        __syncthreads();
        for (int i = t; i < cnt * F_IN; i += 256) {
            int nn = i >> 7, k = i & 127;
            xs[nn][k] = x[(size_t)(base + nn) * F_IN + k];
        }
        __syncthreads();
        int nn = t >> 4, c = t & 15;
        if (nn < cnt) {
            float a0 = 0.f, a1 = 0.f, a2 = 0.f, a3 = 0.f;
            #pragma unroll
            for (int k = 0; k < F_IN; k += 4) {
                a0 += xs[nn][k + 0] * Ws[(k + 0) * D_DIM + c];
                a1 += xs[nn][k + 1] * Ws[(k + 1) * D_DIM + c];
                a2 += xs[nn][k + 2] * Ws[(k + 2) * D_DIM + c];
                a3 += xs[nn][k + 3] * Ws[(k + 3) * D_DIM + c];
            }
            h0[(size_t)(base + nn) * D_DIM + c] = (a0 + a1) + (a2 + a3) + bs[c];
        }
    }
}

// ---------------------------------------------------------------------------
// Node transform: g = h @ W ; per-head attention dots a_src/a_dst.
// ---------------------------------------------------------------------------
template<int K>
__global__ __launch_bounds__(256) void transform_kernel(
        const float* __restrict__ h, const float* __restrict__ W,
        const float* __restrict__ att_s, const float* __restrict__ att_d,
        float* __restrict__ g, float* __restrict__ a_src, float* __restrict__ a_dst) {
    __shared__ float Ws[K * HD];
    int t = threadIdx.x;
    for (int i = t; i < K * HD; i += 256) Ws[i] = W[i];
    __syncthreads();
    int half = t >> 7;
    int c = t & 127;
    float asc = att_s[c], adc = att_d[c];
    for (int base = blockIdx.x * 2; base < N_NODES; base += gridDim.x * 2) {
        int n = base + half;
        const float* hr = h + (size_t)n * K;
        float a0 = 0.f, a1 = 0.f, a2 = 0.f, a3 = 0.f;
        #pragma unroll
        for (int k = 0; k < K; k += 4) {
            a0 += hr[k + 0] * Ws[(k + 0) * HD + c];
            a1 += hr[k + 1] * Ws[(k + 1) * HD + c];
            a2 += hr[k + 2] * Ws[(k + 2) * HD + c];
            a3 += hr[k + 3] * Ws[(k + 3) * HD + c];
        }
        float acc = (a0 + a1) + (a2 + a3);
        g[(size_t)n * HD + c] = acc;
        float ps = acc * asc, pd = acc * adc;
        #pragma unroll
        for (int m = 1; m < 16; m <<= 1) {
            ps += __shfl_xor(ps, m);
            pd += __shfl_xor(pd, m);
        }
        if ((c & 15) == 0) {
            a_src[(size_t)n * H_HEADS + (c >> 4)] = ps;
            a_dst[(size_t)n * H_HEADS + (c >> 4)] = pd;
        }
    }
}

// ---------------------------------------------------------------------------
// CSR build: histogram -> single-block scan -> scatter. Built once, used twice.
// ---------------------------------------------------------------------------
__global__ __launch_bounds__(256) void hist_kernel(
        const int* __restrict__ ei, int* __restrict__ deg) {
    int e = blockIdx.x * 256 + threadIdx.x;
    if (e < E_EDGES) atomicAdd(&deg[ei[E_EDGES + e]], 1);
}

__global__ __launch_bounds__(1024) void scan_kernel(
        const int* __restrict__ deg, int* __restrict__ row_ptr,
        int* __restrict__ fill) {
    __shared__ int part[1024];
    int t = threadIdx.x;
    const int CH = (N_NODES + 1023) / 1024;           // 98
    int lo = t * CH, hi = min(lo + CH, N_NODES);
    int s = 0;
    for (int i = lo; i < hi; ++i) s += deg[i];
    part[t] = s;
    __syncthreads();
    int val = s;
    for (int off = 1; off < 1024; off <<= 1) {
        int other = (t >= off) ? part[t - off] : 0;
        __syncthreads();
        val += other;
        part[t] = val;
        __syncthreads();
    }
    int run = val - s;                                 // exclusive prefix
    for (int i = lo; i < hi; ++i) {
        row_ptr[i] = run; fill[i] = run;
        run += deg[i];
    }
    if (t == 1023) row_ptr[N_NODES] = run;             // == E
}

__global__ __launch_bounds__(256) void scatter_kernel(
        const int* __restrict__ ei, int* __restrict__ fill,
        int* __restrict__ col) {
    int e = blockIdx.x * 256 + threadIdx.x;
    if (e < E_EDGES) {
        int d = ei[E_EDGES + e];
        int p = atomicAdd(&fill[d], 1);
        col[p] = ei[e];
    }
}

// ---------------------------------------------------------------------------
// Fused GAT aggregation over CSR: one wave per dst node. Accumulates the
// unnormalized weighted sum and the softmax denominator together, divides
// and adds bias at the end. Self-loop handled implicitly. No atomics.
// Lane l covers channels l and l+64 (heads l>>4 and l>>4 + 4).
// ---------------------------------------------------------------------------
__global__ __launch_bounds__(256) void gat_aggr_csr_kernel(
        const int* __restrict__ row_ptr, const int* __restrict__ col,
        const float* __restrict__ a_src, const float* __restrict__ a_dst,
        const float* __restrict__ g, const float* __restrict__ bias,
        float* __restrict__ out) {
    int wv = threadIdx.x >> 6, lane = threadIdx.x & 63;
    int d = blockIdx.x * 4 + wv;
    if (d >= N_NODES) return;
    int h1 = lane >> 4, h2 = h1 + 4;
    float ad1 = a_dst[d * 8 + h1], ad2 = a_dst[d * 8 + h2];
    float acc1, acc2, den1, den2;
    {   // self loop (s = d)
        float l1 = a_src[d * 8 + h1] + ad1;
        l1 = (l1 > 0.f) ? l1 : NEG_SLOPE * l1;
        float w1 = __expf(l1);
        float l2 = a_src[d * 8 + h2] + ad2;
        l2 = (l2 > 0.f) ? l2 : NEG_SLOPE * l2;
        float w2 = __expf(l2);
        acc1 = w1 * g[(size_t)d * HD + lane];       den1 = w1;
        acc2 = w2 * g[(size_t)d * HD + lane + 64];  den2 = w2;
    }
    int i = row_ptr[d], end = row_ptr[d + 1];
    for (; i + 2 <= end; i += 2) {                   // 2-wide for MLP
        int sA = col[i], sB = col[i + 1];
        float lA1 = a_src[sA * 8 + h1] + ad1;
        float lA2 = a_src[sA * 8 + h2] + ad2;
        float lB1 = a_src[sB * 8 + h1] + ad1;
        float lB2 = a_src[sB * 8 + h2] + ad2;
        lA1 = (lA1 > 0.f) ? lA1 : NEG_SLOPE * lA1;
        lA2 = (lA2 > 0.f) ? lA2 : NEG_SLOPE * lA2;
        lB1 = (lB1 > 0.f) ? lB1 : NEG_SLOPE * lB1;
        lB2 = (lB2 > 0.f) ? lB2 : NEG_SLOPE * lB2;
        float wA1 = __expf(lA1), wA2 = __expf(lA2);
        float wB1 = __expf(lB1), wB2 = __expf(lB2);
        float gA1 = g[(size_t)sA * HD + lane];
        float gA2 = g[(size_t)sA * HD + lane + 64];
        float gB1 = g[(size_t)sB * HD + lane];
        float gB2 = g[(size_t)sB * HD + lane + 64];
        acc1 += wA1 * gA1 + wB1 * gB1;  den1 += wA1 + wB1;
        acc2 += wA2 * gA2 + wB2 * gB2;  den2 += wA2 + wB2;
    }
    if (i < end) {
        int s = col[i];
        float l1 = a_src[s * 8 + h1] + ad1;
        l1 = (l1 > 0.f) ? l1 : NEG_SLOPE * l1;
        float w1 = __expf(l1);
        float l2 = a_src[s * 8 + h2] + ad2;
        l2 = (l2 > 0.f) ? l2 : NEG_SLOPE * l2;
        float w2 = __expf(l2);
        acc1 += w1 * g[(size_t)s * HD + lane];       den1 += w1;
        acc2 += w2 * g[(size_t)s * HD + lane + 64];  den2 += w2;
    }
    out[(size_t)d * HD + lane]      = acc1 / (den1 + 1e-16f) + bias[lane];
    out[(size_t)d * HD + lane + 64] = acc2 / (den2 + 1e-16f) + bias[lane + 64];
}

// ---------------------------------------------------------------------------
// Heads
// ---------------------------------------------------------------------------
__global__ __launch_bounds__(256) void head_kernel(
        const float* __restrict__ h,
        const float* __restrict__ Wy1, const float* __restrict__ by1,
        const float* __restrict__ Wy0, const float* __restrict__ by0,
        const float* __restrict__ Wc1, const float* __restrict__ bc1,
        const float* __restrict__ Wc2, const float* __restrict__ bc2,
        float* __restrict__ out) {
    int wv = threadIdx.x >> 6, lane = threadIdx.x & 63;
    int n = blockIdx.x * 4 + wv;
    if (n >= N_NODES) return;
    float hA = h[(size_t)n * HD + lane];
    float hB = h[(size_t)n * HD + lane + 64];
    float p = hA * (Wy1[lane] - Wy0[lane]) + hB * (Wy1[lane + 64] - Wy0[lane + 64]);
    #pragma unroll
    for (int m = 1; m < 64; m <<= 1) p += __shfl_xor(p, m);
    float acc2 = 0.f;
    #pragma unroll
    for (int j = 0; j < D_DIM; ++j) {
        float q = hA * Wc1[lane * D_DIM + j] + hB * Wc1[(lane + 64) * D_DIM + j];
        #pragma unroll
        for (int m = 1; m < 64; m <<= 1) q += __shfl_xor(q, m);
        float z = q + bc1[j];
        z = (z > 0.f) ? z : 0.f;
        acc2 += z * Wc2[j];
    }
    if (lane == 0) {
        out[n] = p + by1[0] - by0[0];
        out[N_NODES + n] = 1.f / (1.f + __expf(-(acc2 + bc2[0])));
    }
}

// ---------------------------------------------------------------------------
extern "C" void kernel_launch(void* const* d_in, const int* in_sizes, int n_in,
                              void* d_out, int out_size, void* d_ws, size_t ws_size,
                              hipStream_t stream) {
    const float* x     = (const float*)d_in[0];
    const int*   ei    = (const int*)  d_in[1];
    const float* W_emb = (const float*)d_in[2];
    const float* b_emb = (const float*)d_in[3];
    const float* W0    = (const float*)d_in[4];
    const float* as0   = (const float*)d_in[5];
    const float* ad0   = (const float*)d_in[6];
    const float* b0    = (const float*)d_in[7];
    const float* W1    = (const float*)d_in[8];
    const float* as1   = (const float*)d_in[9];
    const float* ad1   = (const float*)d_in[10];
    const float* b1    = (const float*)d_in[11];
    const float* Wy1   = (const float*)d_in[12];
    const float* by1   = (const float*)d_in[13];
    const float* Wy0   = (const float*)d_in[14];
    const float* by0   = (const float*)d_in[15];
    const float* Wc1   = (const float*)d_in[16];
    const float* bc1   = (const float*)d_in[17];
    const float* Wc2   = (const float*)d_in[18];
    const float* bc2   = (const float*)d_in[19];
    float* out = (float*)d_out;

    float* ws    = (float*)d_ws;
    float* bufG  = ws;                                   // N*128
    float* bufH  = bufG + (size_t)N_NODES * HD;          // N*128
    float* h0    = bufH + (size_t)N_NODES * HD;          // N*16
    float* a_s   = h0   + (size_t)N_NODES * D_DIM;       // N*8
    float* a_d   = a_s  + (size_t)N_NODES * H_HEADS;     // N*8
    int*   deg     = (int*)(a_d + (size_t)N_NODES * H_HEADS);  // N
    int*   fill    = deg + N_NODES;                            // N
    int*   row_ptr = fill + N_NODES;                           // N+1
    int*   col     = row_ptr + (N_NODES + 1);                  // E

    int edgeBlocks = (E_EDGES + 255) / 256;
    int aggrBlocks = (N_NODES + 3) / 4;

    // ----- CSR build (once; reused by both layers) -----
    hipMemsetAsync(deg, 0, (size_t)N_NODES * sizeof(int), stream);
    hipLaunchKernelGGL(hist_kernel, dim3(edgeBlocks), dim3(256), 0, stream, ei, deg);
    hipLaunchKernelGGL(scan_kernel, dim3(1), dim3(1024), 0, stream, deg, row_ptr, fill);
    hipLaunchKernelGGL(scatter_kernel, dim3(edgeBlocks), dim3(256), 0, stream,
                       ei, fill, col);

    // ----- Embedding -----
    hipLaunchKernelGGL(embed_kernel, dim3(512), dim3(256), 0, stream,
                       x, W_emb, b_emb, h0);

    // ----- GAT layer 0 (K = 16) -----
    hipLaunchKernelGGL(transform_kernel<16>, dim3(1024), dim3(256), 0, stream,
                       h0, W0, as0, ad0, bufG, a_s, a_d);
    hipLaunchKernelGGL(gat_aggr_csr_kernel, dim3(aggrBlocks), dim3(256), 0, stream,
                       row_ptr, col, a_s, a_d, bufG, b0, bufH);

    // ----- GAT layer 1 (K = 128) -----
    hipLaunchKernelGGL(transform_kernel<128>, dim3(1024), dim3(256), 0, stream,
                       bufH, W1, as1, ad1, bufG, a_s, a_d);
    hipLaunchKernelGGL(gat_aggr_csr_kernel, dim3(aggrBlocks), dim3(256), 0, stream,
                       row_ptr, col, a_s, a_d, bufG, b1, bufH);

    // ----- Heads -----
    hipLaunchKernelGGL(head_kernel, dim3((N_NODES + 3) / 4), dim3(256), 0, stream,
                       bufH, Wy1, by1, Wy0, by0, Wc1, bc1, Wc2, bc2, out);
}

// Round 3
// 886.006 us; speedup vs baseline: 2.2066x; 1.2420x over previous
//
#include <hip/hip_runtime.h>
#include <math.h>

#define N_NODES 100000
#define E_EDGES 1600000
#define F_IN 128
#define D_DIM 16
#define H_HEADS 8
#define HD 128
#define NEG_SLOPE 0.2f

#define SCAN_BLOCKS 256
#define SCAN_T 256
#define SCAN_CH ((N_NODES + SCAN_BLOCKS - 1) / SCAN_BLOCKS)   // 391

// ---------------------------------------------------------------------------
// Embedding: h0[n, 0..15] = x[n, :] @ W_emb + b_emb
// ---------------------------------------------------------------------------
__global__ __launch_bounds__(256) void embed_kernel(
        const float* __restrict__ x, const float* __restrict__ W,
        const float* __restrict__ b, float* __restrict__ h0) {
    __shared__ float Ws[F_IN * D_DIM];   // 8 KB
    __shared__ float bs[D_DIM];
    __shared__ float xs[16][F_IN + 1];
    int t = threadIdx.x;
    for (int i = t; i < F_IN * D_DIM; i += 256) Ws[i] = W[i];
    if (t < D_DIM) bs[t] = b[t];
    __syncthreads();
    for (int base = blockIdx.x * 16; base < N_NODES; base += gridDim.x * 16) {
        int cnt = min(16, N_NODES - base);
        __syncthreads();
        for (int i = t; i < cnt * F_IN; i += 256) {
            int nn = i >> 7, k = i & 127;
            xs[nn][k] = x[(size_t)(base + nn) * F_IN + k];
        }
        __syncthreads();
        int nn = t >> 4, c = t & 15;
        if (nn < cnt) {
            float a0 = 0.f, a1 = 0.f, a2 = 0.f, a3 = 0.f;
            #pragma unroll
            for (int k = 0; k < F_IN; k += 4) {
                a0 += xs[nn][k + 0] * Ws[(k + 0) * D_DIM + c];
                a1 += xs[nn][k + 1] * Ws[(k + 1) * D_DIM + c];
                a2 += xs[nn][k + 2] * Ws[(k + 2) * D_DIM + c];
                a3 += xs[nn][k + 3] * Ws[(k + 3) * D_DIM + c];
            }
            h0[(size_t)(base + nn) * D_DIM + c] = (a0 + a1) + (a2 + a3) + bs[c];
        }
    }
}

// ---------------------------------------------------------------------------
// Node transform: g = h @ W ; per-head attention dots a_src/a_dst.
// ---------------------------------------------------------------------------
template<int K>
__global__ __launch_bounds__(256) void transform_kernel(
        const float* __restrict__ h, const float* __restrict__ W,
        const float* __restrict__ att_s, const float* __restrict__ att_d,
        float* __restrict__ g, float* __restrict__ a_src, float* __restrict__ a_dst) {
    __shared__ float Ws[K * HD];
    int t = threadIdx.x;
    for (int i = t; i < K * HD; i += 256) Ws[i] = W[i];
    __syncthreads();
    int half = t >> 7;
    int c = t & 127;
    float asc = att_s[c], adc = att_d[c];
    for (int base = blockIdx.x * 2; base < N_NODES; base += gridDim.x * 2) {
        int n = base + half;
        const float* hr = h + (size_t)n * K;
        float a0 = 0.f, a1 = 0.f, a2 = 0.f, a3 = 0.f;
        #pragma unroll
        for (int k = 0; k < K; k += 4) {
            a0 += hr[k + 0] * Ws[(k + 0) * HD + c];
            a1 += hr[k + 1] * Ws[(k + 1) * HD + c];
            a2 += hr[k + 2] * Ws[(k + 2) * HD + c];
            a3 += hr[k + 3] * Ws[(k + 3) * HD + c];
        }
        float acc = (a0 + a1) + (a2 + a3);
        g[(size_t)n * HD + c] = acc;
        float ps = acc * asc, pd = acc * adc;
        #pragma unroll
        for (int m = 1; m < 16; m <<= 1) {
            ps += __shfl_xor(ps, m);
            pd += __shfl_xor(pd, m);
        }
        if ((c & 15) == 0) {
            a_src[(size_t)n * H_HEADS + (c >> 4)] = ps;
            a_dst[(size_t)n * H_HEADS + (c >> 4)] = pd;
        }
    }
}

// ---------------------------------------------------------------------------
// CSR build: histogram -> 3-phase multi-block scan -> scatter.
// ---------------------------------------------------------------------------
__global__ __launch_bounds__(256) void hist_kernel(
        const int* __restrict__ ei, int* __restrict__ deg) {
    int e = blockIdx.x * 256 + threadIdx.x;
    if (e < E_EDGES) atomicAdd(&deg[ei[E_EDGES + e]], 1);
}

// Phase 1: per-block chunk sums (coalesced)
__global__ __launch_bounds__(SCAN_T) void block_sum_kernel(
        const int* __restrict__ deg, int* __restrict__ bsum) {
    int b = blockIdx.x, t = threadIdx.x;
    int lo = b * SCAN_CH, hi = min(lo + SCAN_CH, N_NODES);
    int s = 0;
    for (int i = lo + t; i < hi; i += SCAN_T) s += deg[i];
    #pragma unroll
    for (int m = 1; m < 64; m <<= 1) s += __shfl_xor(s, m);
    __shared__ int ws[SCAN_T / 64];
    if ((t & 63) == 0) ws[t >> 6] = s;
    __syncthreads();
    if (t == 0) {
        int tot = 0;
        #pragma unroll
        for (int w = 0; w < SCAN_T / 64; ++w) tot += ws[w];
        bsum[b] = tot;
    }
}

// Phase 2: exclusive scan of the 256 block sums (1 block)
__global__ __launch_bounds__(SCAN_BLOCKS) void offset_scan_kernel(
        const int* __restrict__ bsum, int* __restrict__ boff) {
    __shared__ int tmp[SCAN_BLOCKS];
    int t = threadIdx.x;
    int v = bsum[t];
    tmp[t] = v;
    __syncthreads();
    int val = v;
    for (int off = 1; off < SCAN_BLOCKS; off <<= 1) {
        int o = (t >= off) ? tmp[t - off] : 0;
        __syncthreads();
        val += o;
        tmp[t] = val;
        __syncthreads();
    }
    boff[t] = val - v;    // exclusive
}

// Phase 3: per-chunk exclusive scan with carry; writes row_ptr + fill
__global__ __launch_bounds__(SCAN_T) void row_ptr_kernel(
        const int* __restrict__ deg, const int* __restrict__ boff,
        int* __restrict__ row_ptr, int* __restrict__ fill) {
    int b = blockIdx.x, t = threadIdx.x;
    int lo = b * SCAN_CH, hi = min(lo + SCAN_CH, N_NODES);
    __shared__ int tmp[SCAN_T];
    __shared__ int carry;
    if (t == 0) carry = boff[b];
    __syncthreads();
    for (int base = lo; base < hi; base += SCAN_T) {
        int i = base + t;
        int v = (i < hi) ? deg[i] : 0;
        tmp[t] = v;
        __syncthreads();
        int val = v;
        for (int off = 1; off < SCAN_T; off <<= 1) {
            int o = (t >= off) ? tmp[t - off] : 0;
            __syncthreads();
            val += o;
            tmp[t] = val;
            __syncthreads();
        }
        int excl = val - v + carry;
        if (i < hi) { row_ptr[i] = excl; fill[i] = excl; }
        __syncthreads();
        if (t == SCAN_T - 1) carry = carry + val;
        __syncthreads();
    }
    if (b == SCAN_BLOCKS - 1 && t == 0) row_ptr[N_NODES] = carry;  // == E
}

__global__ __launch_bounds__(256) void scatter_kernel(
        const int* __restrict__ ei, int* __restrict__ fill,
        int* __restrict__ col) {
    int e = blockIdx.x * 256 + threadIdx.x;
    if (e < E_EDGES) {
        int d = ei[E_EDGES + e];
        int p = atomicAdd(&fill[d], 1);
        col[p] = ei[e];
    }
}

// ---------------------------------------------------------------------------
// Fused GAT aggregation over CSR: one wave per dst node, no atomics.
// ---------------------------------------------------------------------------
__global__ __launch_bounds__(256) void gat_aggr_csr_kernel(
        const int* __restrict__ row_ptr, const int* __restrict__ col,
        const float* __restrict__ a_src, const float* __restrict__ a_dst,
        const float* __restrict__ g, const float* __restrict__ bias,
        float* __restrict__ out) {
    int wv = threadIdx.x >> 6, lane = threadIdx.x & 63;
    int d = blockIdx.x * 4 + wv;
    if (d >= N_NODES) return;
    int h1 = lane >> 4, h2 = h1 + 4;
    float ad1 = a_dst[d * 8 + h1], ad2 = a_dst[d * 8 + h2];
    float acc1, acc2, den1, den2;
    {   // self loop (s = d)
        float l1 = a_src[d * 8 + h1] + ad1;
        l1 = (l1 > 0.f) ? l1 : NEG_SLOPE * l1;
        float w1 = __expf(l1);
        float l2 = a_src[d * 8 + h2] + ad2;
        l2 = (l2 > 0.f) ? l2 : NEG_SLOPE * l2;
        float w2 = __expf(l2);
        acc1 = w1 * g[(size_t)d * HD + lane];       den1 = w1;
        acc2 = w2 * g[(size_t)d * HD + lane + 64];  den2 = w2;
    }
    int i = row_ptr[d], end = row_ptr[d + 1];
    for (; i + 2 <= end; i += 2) {
        int sA = col[i], sB = col[i + 1];
        float lA1 = a_src[sA * 8 + h1] + ad1;
        float lA2 = a_src[sA * 8 + h2] + ad2;
        float lB1 = a_src[sB * 8 + h1] + ad1;
        float lB2 = a_src[sB * 8 + h2] + ad2;
        lA1 = (lA1 > 0.f) ? lA1 : NEG_SLOPE * lA1;
        lA2 = (lA2 > 0.f) ? lA2 : NEG_SLOPE * lA2;
        lB1 = (lB1 > 0.f) ? lB1 : NEG_SLOPE * lB1;
        lB2 = (lB2 > 0.f) ? lB2 : NEG_SLOPE * lB2;
        float wA1 = __expf(lA1), wA2 = __expf(lA2);
        float wB1 = __expf(lB1), wB2 = __expf(lB2);
        float gA1 = g[(size_t)sA * HD + lane];
        float gA2 = g[(size_t)sA * HD + lane + 64];
        float gB1 = g[(size_t)sB * HD + lane];
        float gB2 = g[(size_t)sB * HD + lane + 64];
        acc1 += wA1 * gA1 + wB1 * gB1;  den1 += wA1 + wB1;
        acc2 += wA2 * gA2 + wB2 * gB2;  den2 += wA2 + wB2;
    }
    if (i < end) {
        int s = col[i];
        float l1 = a_src[s * 8 + h1] + ad1;
        l1 = (l1 > 0.f) ? l1 : NEG_SLOPE * l1;
        float w1 = __expf(l1);
        float l2 = a_src[s * 8 + h2] + ad2;
        l2 = (l2 > 0.f) ? l2 : NEG_SLOPE * l2;
        float w2 = __expf(l2);
        acc1 += w1 * g[(size_t)s * HD + lane];       den1 += w1;
        acc2 += w2 * g[(size_t)s * HD + lane + 64];  den2 += w2;
    }
    out[(size_t)d * HD + lane]      = acc1 / (den1 + 1e-16f) + bias[lane];
    out[(size_t)d * HD + lane + 64] = acc2 / (den2 + 1e-16f) + bias[lane + 64];
}

// ---------------------------------------------------------------------------
// Heads
// ---------------------------------------------------------------------------
__global__ __launch_bounds__(256) void head_kernel(
        const float* __restrict__ h,
        const float* __restrict__ Wy1, const float* __restrict__ by1,
        const float* __restrict__ Wy0, const float* __restrict__ by0,
        const float* __restrict__ Wc1, const float* __restrict__ bc1,
        const float* __restrict__ Wc2, const float* __restrict__ bc2,
        float* __restrict__ out) {
    int wv = threadIdx.x >> 6, lane = threadIdx.x & 63;
    int n = blockIdx.x * 4 + wv;
    if (n >= N_NODES) return;
    float hA = h[(size_t)n * HD + lane];
    float hB = h[(size_t)n * HD + lane + 64];
    float p = hA * (Wy1[lane] - Wy0[lane]) + hB * (Wy1[lane + 64] - Wy0[lane + 64]);
    #pragma unroll
    for (int m = 1; m < 64; m <<= 1) p += __shfl_xor(p, m);
    float acc2 = 0.f;
    #pragma unroll
    for (int j = 0; j < D_DIM; ++j) {
        float q = hA * Wc1[lane * D_DIM + j] + hB * Wc1[(lane + 64) * D_DIM + j];
        #pragma unroll
        for (int m = 1; m < 64; m <<= 1) q += __shfl_xor(q, m);
        float z = q + bc1[j];
        z = (z > 0.f) ? z : 0.f;
        acc2 += z * Wc2[j];
    }
    if (lane == 0) {
        out[n] = p + by1[0] - by0[0];
        out[N_NODES + n] = 1.f / (1.f + __expf(-(acc2 + bc2[0])));
    }
}

// ---------------------------------------------------------------------------
extern "C" void kernel_launch(void* const* d_in, const int* in_sizes, int n_in,
                              void* d_out, int out_size, void* d_ws, size_t ws_size,
                              hipStream_t stream) {
    const float* x     = (const float*)d_in[0];
    const int*   ei    = (const int*)  d_in[1];
    const float* W_emb = (const float*)d_in[2];
    const float* b_emb = (const float*)d_in[3];
    const float* W0    = (const float*)d_in[4];
    const float* as0   = (const float*)d_in[5];
    const float* ad0   = (const float*)d_in[6];
    const float* b0    = (const float*)d_in[7];
    const float* W1    = (const float*)d_in[8];
    const float* as1   = (const float*)d_in[9];
    const float* ad1   = (const float*)d_in[10];
    const float* b1    = (const float*)d_in[11];
    const float* Wy1   = (const float*)d_in[12];
    const float* by1   = (const float*)d_in[13];
    const float* Wy0   = (const float*)d_in[14];
    const float* by0   = (const float*)d_in[15];
    const float* Wc1   = (const float*)d_in[16];
    const float* bc1   = (const float*)d_in[17];
    const float* Wc2   = (const float*)d_in[18];
    const float* bc2   = (const float*)d_in[19];
    float* out = (float*)d_out;

    float* ws    = (float*)d_ws;
    float* bufG  = ws;                                   // N*128
    float* bufH  = bufG + (size_t)N_NODES * HD;          // N*128
    float* h0    = bufH + (size_t)N_NODES * HD;          // N*16
    float* a_s   = h0   + (size_t)N_NODES * D_DIM;       // N*8
    float* a_d   = a_s  + (size_t)N_NODES * H_HEADS;     // N*8
    int*   deg     = (int*)(a_d + (size_t)N_NODES * H_HEADS);  // N
    int*   fill    = deg + N_NODES;                            // N
    int*   row_ptr = fill + N_NODES;                           // N+1
    int*   bsum    = row_ptr + (N_NODES + 1);                  // 256
    int*   boff    = bsum + SCAN_BLOCKS;                       // 256
    int*   col     = boff + SCAN_BLOCKS;                       // E

    int edgeBlocks = (E_EDGES + 255) / 256;
    int aggrBlocks = (N_NODES + 3) / 4;

    // ----- CSR build (once; reused by both layers) -----
    hipMemsetAsync(deg, 0, (size_t)N_NODES * sizeof(int), stream);
    hipLaunchKernelGGL(hist_kernel, dim3(edgeBlocks), dim3(256), 0, stream, ei, deg);
    hipLaunchKernelGGL(block_sum_kernel, dim3(SCAN_BLOCKS), dim3(SCAN_T), 0, stream,
                       deg, bsum);
    hipLaunchKernelGGL(offset_scan_kernel, dim3(1), dim3(SCAN_BLOCKS), 0, stream,
                       bsum, boff);
    hipLaunchKernelGGL(row_ptr_kernel, dim3(SCAN_BLOCKS), dim3(SCAN_T), 0, stream,
                       deg, boff, row_ptr, fill);
    hipLaunchKernelGGL(scatter_kernel, dim3(edgeBlocks), dim3(256), 0, stream,
                       ei, fill, col);

    // ----- Embedding -----
    hipLaunchKernelGGL(embed_kernel, dim3(512), dim3(256), 0, stream,
                       x, W_emb, b_emb, h0);

    // ----- GAT layer 0 (K = 16) -----
    hipLaunchKernelGGL(transform_kernel<16>, dim3(1024), dim3(256), 0, stream,
                       h0, W0, as0, ad0, bufG, a_s, a_d);
    hipLaunchKernelGGL(gat_aggr_csr_kernel, dim3(aggrBlocks), dim3(256), 0, stream,
                       row_ptr, col, a_s, a_d, bufG, b0, bufH);

    // ----- GAT layer 1 (K = 128) -----
    hipLaunchKernelGGL(transform_kernel<128>, dim3(1024), dim3(256), 0, stream,
                       bufH, W1, as1, ad1, bufG, a_s, a_d);
    hipLaunchKernelGGL(gat_aggr_csr_kernel, dim3(aggrBlocks), dim3(256), 0, stream,
                       row_ptr, col, a_s, a_d, bufG, b1, bufH);

    // ----- Heads -----
    hipLaunchKernelGGL(head_kernel, dim3((N_NODES + 3) / 4), dim3(256), 0, stream,
                       bufH, Wy1, by1, Wy0, by0, Wc1, bc1, Wc2, bc2, out);
}

// Round 4
// 746.462 us; speedup vs baseline: 2.6191x; 1.1869x over previous
//
#include <hip/hip_runtime.h>
#include <math.h>

#define N_NODES 100000
#define E_EDGES 1600000
#define F_IN 128
#define D_DIM 16
#define H_HEADS 8
#define HD 128
#define NEG_SLOPE 0.2f

#define SCAN_BLOCKS 256
#define SCAN_T 256
#define SCAN_CH ((N_NODES + SCAN_BLOCKS - 1) / SCAN_BLOCKS)   // 391

#define NTILES ((N_NODES + 63) / 64)        // 1563 node-tiles of 64

// ---------------------------------------------------------------------------
// Embedding: h0[n, 0..15] = x[n, :] @ W_emb + b_emb
// ---------------------------------------------------------------------------
__global__ __launch_bounds__(256) void embed_kernel(
        const float* __restrict__ x, const float* __restrict__ W,
        const float* __restrict__ b, float* __restrict__ h0) {
    __shared__ float Ws[F_IN * D_DIM];   // 8 KB
    __shared__ float bs[D_DIM];
    __shared__ float xs[16][F_IN + 1];
    int t = threadIdx.x;
    for (int i = t; i < F_IN * D_DIM; i += 256) Ws[i] = W[i];
    if (t < D_DIM) bs[t] = b[t];
    __syncthreads();
    for (int base = blockIdx.x * 16; base < N_NODES; base += gridDim.x * 16) {
        int cnt = min(16, N_NODES - base);
        __syncthreads();
        for (int i = t; i < cnt * F_IN; i += 256) {
            int nn = i >> 7, k = i & 127;
            xs[nn][k] = x[(size_t)(base + nn) * F_IN + k];
        }
        __syncthreads();
        int nn = t >> 4, c = t & 15;
        if (nn < cnt) {
            float a0 = 0.f, a1 = 0.f, a2 = 0.f, a3 = 0.f;
            #pragma unroll
            for (int k = 0; k < F_IN; k += 4) {
                a0 += xs[nn][k + 0] * Ws[(k + 0) * D_DIM + c];
                a1 += xs[nn][k + 1] * Ws[(k + 1) * D_DIM + c];
                a2 += xs[nn][k + 2] * Ws[(k + 2) * D_DIM + c];
                a3 += xs[nn][k + 3] * Ws[(k + 3) * D_DIM + c];
            }
            h0[(size_t)(base + nn) * D_DIM + c] = (a0 + a1) + (a2 + a3) + bs[c];
        }
    }
}

// ---------------------------------------------------------------------------
// Node transform as register-tiled GEMM: [N,K] @ [K,128] -> g, + attn dots.
// Work item = (node-tile of 64) x (channel half of 64).
// Block 256 threads: thread = 4 nodes x 4 channels; k unrolled by 4, float4
// LDS reads -> 8 ds_read_b128 per 64 FMAs.
// ---------------------------------------------------------------------------
template<int K>
__global__ __launch_bounds__(256) void transform_gemm_kernel(
        const float* __restrict__ h, const float* __restrict__ W,
        const float* __restrict__ att_s, const float* __restrict__ att_d,
        float* __restrict__ g, float* __restrict__ a_src, float* __restrict__ a_dst) {
    __shared__ float Ws[K][64];          // K=128: 32 KB, K=16: 4 KB
    __shared__ float hs[64][K + 4];      // pad +4 floats: break row-bank stack
    int t = threadIdx.x;
    int cq = t & 15;                     // channel quad within half (0..15)
    int nq = t >> 4;                     // node quad (0..15)
    constexpr int KSH = (K == 128) ? 7 : 4;

    for (int item = blockIdx.x; item < NTILES * 2; item += gridDim.x) {
        int tile = item >> 1;
        int coff = (item & 1) << 6;                 // 0 or 64
        int nbase = tile << 6;
        __syncthreads();                            // protect prev iter reads
        // stage W column-half: K x 64
        for (int i = t; i < K * 64; i += 256)
            Ws[i >> 6][i & 63] = W[(size_t)(i >> 6) * HD + coff + (i & 63)];
        // stage 64 h rows (clamped in tail tile)
        for (int i = t; i < (K << 6); i += 256) {
            int r = i >> KSH, k = i & (K - 1);
            int n = nbase + r; if (n >= N_NODES) n = N_NODES - 1;
            hs[r][k] = h[(size_t)n * K + k];
        }
        __syncthreads();

        float acc[4][4] = {{0.f}};
        #pragma unroll 2
        for (int k = 0; k < K; k += 4) {
            float4 w0 = *(const float4*)&Ws[k + 0][cq << 2];
            float4 w1 = *(const float4*)&Ws[k + 1][cq << 2];
            float4 w2 = *(const float4*)&Ws[k + 2][cq << 2];
            float4 w3 = *(const float4*)&Ws[k + 3][cq << 2];
            #pragma unroll
            for (int j = 0; j < 4; ++j) {
                float4 hv = *(const float4*)&hs[(nq << 2) + j][k];
                acc[j][0] += hv.x * w0.x + hv.y * w1.x + hv.z * w2.x + hv.w * w3.x;
                acc[j][1] += hv.x * w0.y + hv.y * w1.y + hv.z * w2.y + hv.w * w3.y;
                acc[j][2] += hv.x * w0.z + hv.y * w1.z + hv.z * w2.z + hv.w * w3.z;
                acc[j][3] += hv.x * w0.w + hv.y * w1.w + hv.z * w2.w + hv.w * w3.w;
            }
        }

        int c0 = coff + (cq << 2);
        float as0 = att_s[c0], as1 = att_s[c0 + 1], as2 = att_s[c0 + 2], as3 = att_s[c0 + 3];
        float ad0 = att_d[c0], ad1 = att_d[c0 + 1], ad2 = att_d[c0 + 2], ad3 = att_d[c0 + 3];
        int head = c0 >> 4;
        #pragma unroll
        for (int j = 0; j < 4; ++j) {
            int n = nbase + (nq << 2) + j;
            float ps = acc[j][0] * as0 + acc[j][1] * as1 + acc[j][2] * as2 + acc[j][3] * as3;
            float pd = acc[j][0] * ad0 + acc[j][1] * ad1 + acc[j][2] * ad2 + acc[j][3] * ad3;
            ps += __shfl_xor(ps, 1); ps += __shfl_xor(ps, 2);
            pd += __shfl_xor(pd, 1); pd += __shfl_xor(pd, 2);
            if (n < N_NODES) {
                *(float4*)&g[(size_t)n * HD + c0] =
                    make_float4(acc[j][0], acc[j][1], acc[j][2], acc[j][3]);
                if ((cq & 3) == 0) {
                    a_src[(size_t)n * H_HEADS + head] = ps;
                    a_dst[(size_t)n * H_HEADS + head] = pd;
                }
            }
        }
    }
}

// ---------------------------------------------------------------------------
// CSR build: histogram -> 3-phase multi-block scan -> scatter.
// ---------------------------------------------------------------------------
__global__ __launch_bounds__(256) void hist_kernel(
        const int* __restrict__ ei, int* __restrict__ deg) {
    int e = blockIdx.x * 256 + threadIdx.x;
    if (e < E_EDGES) atomicAdd(&deg[ei[E_EDGES + e]], 1);
}

__global__ __launch_bounds__(SCAN_T) void block_sum_kernel(
        const int* __restrict__ deg, int* __restrict__ bsum) {
    int b = blockIdx.x, t = threadIdx.x;
    int lo = b * SCAN_CH, hi = min(lo + SCAN_CH, N_NODES);
    int s = 0;
    for (int i = lo + t; i < hi; i += SCAN_T) s += deg[i];
    #pragma unroll
    for (int m = 1; m < 64; m <<= 1) s += __shfl_xor(s, m);
    __shared__ int ws[SCAN_T / 64];
    if ((t & 63) == 0) ws[t >> 6] = s;
    __syncthreads();
    if (t == 0) {
        int tot = 0;
        #pragma unroll
        for (int w = 0; w < SCAN_T / 64; ++w) tot += ws[w];
        bsum[b] = tot;
    }
}

__global__ __launch_bounds__(SCAN_BLOCKS) void offset_scan_kernel(
        const int* __restrict__ bsum, int* __restrict__ boff) {
    __shared__ int tmp[SCAN_BLOCKS];
    int t = threadIdx.x;
    int v = bsum[t];
    tmp[t] = v;
    __syncthreads();
    int val = v;
    for (int off = 1; off < SCAN_BLOCKS; off <<= 1) {
        int o = (t >= off) ? tmp[t - off] : 0;
        __syncthreads();
        val += o;
        tmp[t] = val;
        __syncthreads();
    }
    boff[t] = val - v;    // exclusive
}

__global__ __launch_bounds__(SCAN_T) void row_ptr_kernel(
        const int* __restrict__ deg, const int* __restrict__ boff,
        int* __restrict__ row_ptr, int* __restrict__ fill) {
    int b = blockIdx.x, t = threadIdx.x;
    int lo = b * SCAN_CH, hi = min(lo + SCAN_CH, N_NODES);
    __shared__ int tmp[SCAN_T];
    __shared__ int carry;
    if (t == 0) carry = boff[b];
    __syncthreads();
    for (int base = lo; base < hi; base += SCAN_T) {
        int i = base + t;
        int v = (i < hi) ? deg[i] : 0;
        tmp[t] = v;
        __syncthreads();
        int val = v;
        for (int off = 1; off < SCAN_T; off <<= 1) {
            int o = (t >= off) ? tmp[t - off] : 0;
            __syncthreads();
            val += o;
            tmp[t] = val;
            __syncthreads();
        }
        int excl = val - v + carry;
        if (i < hi) { row_ptr[i] = excl; fill[i] = excl; }
        __syncthreads();
        if (t == SCAN_T - 1) carry = carry + val;
        __syncthreads();
    }
    if (b == SCAN_BLOCKS - 1 && t == 0) row_ptr[N_NODES] = carry;  // == E
}

__global__ __launch_bounds__(256) void scatter_kernel(
        const int* __restrict__ ei, int* __restrict__ fill,
        int* __restrict__ col) {
    int e = blockIdx.x * 256 + threadIdx.x;
    if (e < E_EDGES) {
        int d = ei[E_EDGES + e];
        int p = atomicAdd(&fill[d], 1);
        col[p] = ei[e];
    }
}

// ---------------------------------------------------------------------------
// Fused GAT aggregation over CSR: one wave per dst node, no atomics.
// ---------------------------------------------------------------------------
__global__ __launch_bounds__(256) void gat_aggr_csr_kernel(
        const int* __restrict__ row_ptr, const int* __restrict__ col,
        const float* __restrict__ a_src, const float* __restrict__ a_dst,
        const float* __restrict__ g, const float* __restrict__ bias,
        float* __restrict__ out) {
    int wv = threadIdx.x >> 6, lane = threadIdx.x & 63;
    int d = blockIdx.x * 4 + wv;
    if (d >= N_NODES) return;
    int h1 = lane >> 4, h2 = h1 + 4;
    float ad1 = a_dst[d * 8 + h1], ad2 = a_dst[d * 8 + h2];
    float acc1, acc2, den1, den2;
    {   // self loop (s = d)
        float l1 = a_src[d * 8 + h1] + ad1;
        l1 = (l1 > 0.f) ? l1 : NEG_SLOPE * l1;
        float w1 = __expf(l1);
        float l2 = a_src[d * 8 + h2] + ad2;
        l2 = (l2 > 0.f) ? l2 : NEG_SLOPE * l2;
        float w2 = __expf(l2);
        acc1 = w1 * g[(size_t)d * HD + lane];       den1 = w1;
        acc2 = w2 * g[(size_t)d * HD + lane + 64];  den2 = w2;
    }
    int i = row_ptr[d], end = row_ptr[d + 1];
    for (; i + 2 <= end; i += 2) {
        int sA = col[i], sB = col[i + 1];
        float lA1 = a_src[sA * 8 + h1] + ad1;
        float lA2 = a_src[sA * 8 + h2] + ad2;
        float lB1 = a_src[sB * 8 + h1] + ad1;
        float lB2 = a_src[sB * 8 + h2] + ad2;
        lA1 = (lA1 > 0.f) ? lA1 : NEG_SLOPE * lA1;
        lA2 = (lA2 > 0.f) ? lA2 : NEG_SLOPE * lA2;
        lB1 = (lB1 > 0.f) ? lB1 : NEG_SLOPE * lB1;
        lB2 = (lB2 > 0.f) ? lB2 : NEG_SLOPE * lB2;
        float wA1 = __expf(lA1), wA2 = __expf(lA2);
        float wB1 = __expf(lB1), wB2 = __expf(lB2);
        float gA1 = g[(size_t)sA * HD + lane];
        float gA2 = g[(size_t)sA * HD + lane + 64];
        float gB1 = g[(size_t)sB * HD + lane];
        float gB2 = g[(size_t)sB * HD + lane + 64];
        acc1 += wA1 * gA1 + wB1 * gB1;  den1 += wA1 + wB1;
        acc2 += wA2 * gA2 + wB2 * gB2;  den2 += wA2 + wB2;
    }
    if (i < end) {
        int s = col[i];
        float l1 = a_src[s * 8 + h1] + ad1;
        l1 = (l1 > 0.f) ? l1 : NEG_SLOPE * l1;
        float w1 = __expf(l1);
        float l2 = a_src[s * 8 + h2] + ad2;
        l2 = (l2 > 0.f) ? l2 : NEG_SLOPE * l2;
        float w2 = __expf(l2);
        acc1 += w1 * g[(size_t)s * HD + lane];       den1 += w1;
        acc2 += w2 * g[(size_t)s * HD + lane + 64];  den2 += w2;
    }
    out[(size_t)d * HD + lane]      = acc1 / (den1 + 1e-16f) + bias[lane];
    out[(size_t)d * HD + lane + 64] = acc2 / (den2 + 1e-16f) + bias[lane + 64];
}

// ---------------------------------------------------------------------------
// Heads
// ---------------------------------------------------------------------------
__global__ __launch_bounds__(256) void head_kernel(
        const float* __restrict__ h,
        const float* __restrict__ Wy1, const float* __restrict__ by1,
        const float* __restrict__ Wy0, const float* __restrict__ by0,
        const float* __restrict__ Wc1, const float* __restrict__ bc1,
        const float* __restrict__ Wc2, const float* __restrict__ bc2,
        float* __restrict__ out) {
    int wv = threadIdx.x >> 6, lane = threadIdx.x & 63;
    int n = blockIdx.x * 4 + wv;
    if (n >= N_NODES) return;
    float hA = h[(size_t)n * HD + lane];
    float hB = h[(size_t)n * HD + lane + 64];
    float p = hA * (Wy1[lane] - Wy0[lane]) + hB * (Wy1[lane + 64] - Wy0[lane + 64]);
    #pragma unroll
    for (int m = 1; m < 64; m <<= 1) p += __shfl_xor(p, m);
    float acc2 = 0.f;
    #pragma unroll
    for (int j = 0; j < D_DIM; ++j) {
        float q = hA * Wc1[lane * D_DIM + j] + hB * Wc1[(lane + 64) * D_DIM + j];
        #pragma unroll
        for (int m = 1; m < 64; m <<= 1) q += __shfl_xor(q, m);
        float z = q + bc1[j];
        z = (z > 0.f) ? z : 0.f;
        acc2 += z * Wc2[j];
    }
    if (lane == 0) {
        out[n] = p + by1[0] - by0[0];
        out[N_NODES + n] = 1.f / (1.f + __expf(-(acc2 + bc2[0])));
    }
}

// ---------------------------------------------------------------------------
extern "C" void kernel_launch(void* const* d_in, const int* in_sizes, int n_in,
                              void* d_out, int out_size, void* d_ws, size_t ws_size,
                              hipStream_t stream) {
    const float* x     = (const float*)d_in[0];
    const int*   ei    = (const int*)  d_in[1];
    const float* W_emb = (const float*)d_in[2];
    const float* b_emb = (const float*)d_in[3];
    const float* W0    = (const float*)d_in[4];
    const float* as0   = (const float*)d_in[5];
    const float* ad0   = (const float*)d_in[6];
    const float* b0    = (const float*)d_in[7];
    const float* W1    = (const float*)d_in[8];
    const float* as1   = (const float*)d_in[9];
    const float* ad1   = (const float*)d_in[10];
    const float* b1    = (const float*)d_in[11];
    const float* Wy1   = (const float*)d_in[12];
    const float* by1   = (const float*)d_in[13];
    const float* Wy0   = (const float*)d_in[14];
    const float* by0   = (const float*)d_in[15];
    const float* Wc1   = (const float*)d_in[16];
    const float* bc1   = (const float*)d_in[17];
    const float* Wc2   = (const float*)d_in[18];
    const float* bc2   = (const float*)d_in[19];
    float* out = (float*)d_out;

    float* ws    = (float*)d_ws;
    float* bufG  = ws;                                   // N*128
    float* bufH  = bufG + (size_t)N_NODES * HD;          // N*128
    float* h0    = bufH + (size_t)N_NODES * HD;          // N*16
    float* a_s   = h0   + (size_t)N_NODES * D_DIM;       // N*8
    float* a_d   = a_s  + (size_t)N_NODES * H_HEADS;     // N*8
    int*   deg     = (int*)(a_d + (size_t)N_NODES * H_HEADS);  // N
    int*   fill    = deg + N_NODES;                            // N
    int*   row_ptr = fill + N_NODES;                           // N+1
    int*   bsum    = row_ptr + (N_NODES + 1);                  // 256
    int*   boff    = bsum + SCAN_BLOCKS;                       // 256
    int*   col     = boff + SCAN_BLOCKS;                       // E

    int edgeBlocks = (E_EDGES + 255) / 256;
    int aggrBlocks = (N_NODES + 3) / 4;

    // ----- CSR build (once; reused by both layers) -----
    hipMemsetAsync(deg, 0, (size_t)N_NODES * sizeof(int), stream);
    hipLaunchKernelGGL(hist_kernel, dim3(edgeBlocks), dim3(256), 0, stream, ei, deg);
    hipLaunchKernelGGL(block_sum_kernel, dim3(SCAN_BLOCKS), dim3(SCAN_T), 0, stream,
                       deg, bsum);
    hipLaunchKernelGGL(offset_scan_kernel, dim3(1), dim3(SCAN_BLOCKS), 0, stream,
                       bsum, boff);
    hipLaunchKernelGGL(row_ptr_kernel, dim3(SCAN_BLOCKS), dim3(SCAN_T), 0, stream,
                       deg, boff, row_ptr, fill);
    hipLaunchKernelGGL(scatter_kernel, dim3(edgeBlocks), dim3(256), 0, stream,
                       ei, fill, col);

    // ----- Embedding -----
    hipLaunchKernelGGL(embed_kernel, dim3(512), dim3(256), 0, stream,
                       x, W_emb, b_emb, h0);

    // ----- GAT layer 0 (K = 16) -----
    hipLaunchKernelGGL(transform_gemm_kernel<16>, dim3(2048), dim3(256), 0, stream,
                       h0, W0, as0, ad0, bufG, a_s, a_d);
    hipLaunchKernelGGL(gat_aggr_csr_kernel, dim3(aggrBlocks), dim3(256), 0, stream,
                       row_ptr, col, a_s, a_d, bufG, b0, bufH);

    // ----- GAT layer 1 (K = 128) -----
    hipLaunchKernelGGL(transform_gemm_kernel<128>, dim3(1024), dim3(256), 0, stream,
                       bufH, W1, as1, ad1, bufG, a_s, a_d);
    hipLaunchKernelGGL(gat_aggr_csr_kernel, dim3(aggrBlocks), dim3(256), 0, stream,
                       row_ptr, col, a_s, a_d, bufG, b1, bufH);

    // ----- Heads -----
    hipLaunchKernelGGL(head_kernel, dim3((N_NODES + 3) / 4), dim3(256), 0, stream,
                       bufH, Wy1, by1, Wy0, by0, Wc1, bc1, Wc2, bc2, out);
}

// Round 5
// 629.288 us; speedup vs baseline: 3.1067x; 1.1862x over previous
//
#include <hip/hip_runtime.h>
#include <hip/hip_fp16.h>
#include <math.h>

#define N_NODES 100000
#define E_EDGES 1600000
#define F_IN 128
#define D_DIM 16
#define H_HEADS 8
#define HD 128
#define NEG_SLOPE 0.2f

#define SCAN_BLOCKS 256
#define SCAN_T 256
#define SCAN_CH ((N_NODES + SCAN_BLOCKS - 1) / SCAN_BLOCKS)   // 391

#define NTILES ((N_NODES + 63) / 64)        // 1563 node-tiles of 64

// ---------------------------------------------------------------------------
// Embedding: h0[n, 0..15] = x[n, :] @ W_emb + b_emb
// ---------------------------------------------------------------------------
__global__ __launch_bounds__(256) void embed_kernel(
        const float* __restrict__ x, const float* __restrict__ W,
        const float* __restrict__ b, float* __restrict__ h0) {
    __shared__ float Ws[F_IN * D_DIM];   // 8 KB
    __shared__ float bs[D_DIM];
    __shared__ float xs[16][F_IN + 1];
    int t = threadIdx.x;
    for (int i = t; i < F_IN * D_DIM; i += 256) Ws[i] = W[i];
    if (t < D_DIM) bs[t] = b[t];
    __syncthreads();
    for (int base = blockIdx.x * 16; base < N_NODES; base += gridDim.x * 16) {
        int cnt = min(16, N_NODES - base);
        __syncthreads();
        for (int i = t; i < cnt * F_IN; i += 256) {
            int nn = i >> 7, k = i & 127;
            xs[nn][k] = x[(size_t)(base + nn) * F_IN + k];
        }
        __syncthreads();
        int nn = t >> 4, c = t & 15;
        if (nn < cnt) {
            float a0 = 0.f, a1 = 0.f, a2 = 0.f, a3 = 0.f;
            #pragma unroll
            for (int k = 0; k < F_IN; k += 4) {
                a0 += xs[nn][k + 0] * Ws[(k + 0) * D_DIM + c];
                a1 += xs[nn][k + 1] * Ws[(k + 1) * D_DIM + c];
                a2 += xs[nn][k + 2] * Ws[(k + 2) * D_DIM + c];
                a3 += xs[nn][k + 3] * Ws[(k + 3) * D_DIM + c];
            }
            h0[(size_t)(base + nn) * D_DIM + c] = (a0 + a1) + (a2 + a3) + bs[c];
        }
    }
}

// ---------------------------------------------------------------------------
// Node transform as register-tiled GEMM: [N,K] @ [K,128] -> g (fp16), + attn
// dots (fp32, computed from fp32 accumulators before rounding).
// ---------------------------------------------------------------------------
template<int K>
__global__ __launch_bounds__(256) void transform_gemm_kernel(
        const float* __restrict__ h, const float* __restrict__ W,
        const float* __restrict__ att_s, const float* __restrict__ att_d,
        __half* __restrict__ g, float* __restrict__ a_src, float* __restrict__ a_dst) {
    __shared__ float Ws[K][64];          // K=128: 32 KB, K=16: 4 KB
    __shared__ float hs[64][K + 4];      // pad +4 floats: break row-bank stack
    int t = threadIdx.x;
    int cq = t & 15;                     // channel quad within half (0..15)
    int nq = t >> 4;                     // node quad (0..15)
    constexpr int KSH = (K == 128) ? 7 : 4;

    for (int item = blockIdx.x; item < NTILES * 2; item += gridDim.x) {
        int tile = item >> 1;
        int coff = (item & 1) << 6;                 // 0 or 64
        int nbase = tile << 6;
        __syncthreads();                            // protect prev iter reads
        // stage W column-half: K x 64
        for (int i = t; i < K * 64; i += 256)
            Ws[i >> 6][i & 63] = W[(size_t)(i >> 6) * HD + coff + (i & 63)];
        // stage 64 h rows (clamped in tail tile)
        for (int i = t; i < (K << 6); i += 256) {
            int r = i >> KSH, k = i & (K - 1);
            int n = nbase + r; if (n >= N_NODES) n = N_NODES - 1;
            hs[r][k] = h[(size_t)n * K + k];
        }
        __syncthreads();

        float acc[4][4] = {{0.f}};
        #pragma unroll 2
        for (int k = 0; k < K; k += 4) {
            float4 w0 = *(const float4*)&Ws[k + 0][cq << 2];
            float4 w1 = *(const float4*)&Ws[k + 1][cq << 2];
            float4 w2 = *(const float4*)&Ws[k + 2][cq << 2];
            float4 w3 = *(const float4*)&Ws[k + 3][cq << 2];
            #pragma unroll
            for (int j = 0; j < 4; ++j) {
                float4 hv = *(const float4*)&hs[(nq << 2) + j][k];
                acc[j][0] += hv.x * w0.x + hv.y * w1.x + hv.z * w2.x + hv.w * w3.x;
                acc[j][1] += hv.x * w0.y + hv.y * w1.y + hv.z * w2.y + hv.w * w3.y;
                acc[j][2] += hv.x * w0.z + hv.y * w1.z + hv.z * w2.z + hv.w * w3.z;
                acc[j][3] += hv.x * w0.w + hv.y * w1.w + hv.z * w2.w + hv.w * w3.w;
            }
        }

        int c0 = coff + (cq << 2);
        float as0 = att_s[c0], as1 = att_s[c0 + 1], as2 = att_s[c0 + 2], as3 = att_s[c0 + 3];
        float ad0 = att_d[c0], ad1 = att_d[c0 + 1], ad2 = att_d[c0 + 2], ad3 = att_d[c0 + 3];
        int head = c0 >> 4;
        #pragma unroll
        for (int j = 0; j < 4; ++j) {
            int n = nbase + (nq << 2) + j;
            float ps = acc[j][0] * as0 + acc[j][1] * as1 + acc[j][2] * as2 + acc[j][3] * as3;
            float pd = acc[j][0] * ad0 + acc[j][1] * ad1 + acc[j][2] * ad2 + acc[j][3] * ad3;
            ps += __shfl_xor(ps, 1); ps += __shfl_xor(ps, 2);
            pd += __shfl_xor(pd, 1); pd += __shfl_xor(pd, 2);
            if (n < N_NODES) {
                union { __half2 h2[2]; uint2 u; } pk;
                pk.h2[0] = __floats2half2_rn(acc[j][0], acc[j][1]);
                pk.h2[1] = __floats2half2_rn(acc[j][2], acc[j][3]);
                *(uint2*)&g[(size_t)n * HD + c0] = pk.u;
                if ((cq & 3) == 0) {
                    a_src[(size_t)n * H_HEADS + head] = ps;
                    a_dst[(size_t)n * H_HEADS + head] = pd;
                }
            }
        }
    }
}

// ---------------------------------------------------------------------------
// CSR build: histogram -> 3-phase multi-block scan -> scatter.
// ---------------------------------------------------------------------------
__global__ __launch_bounds__(256) void hist_kernel(
        const int* __restrict__ ei, int* __restrict__ deg) {
    int e = blockIdx.x * 256 + threadIdx.x;
    if (e < E_EDGES) atomicAdd(&deg[ei[E_EDGES + e]], 1);
}

__global__ __launch_bounds__(SCAN_T) void block_sum_kernel(
        const int* __restrict__ deg, int* __restrict__ bsum) {
    int b = blockIdx.x, t = threadIdx.x;
    int lo = b * SCAN_CH, hi = min(lo + SCAN_CH, N_NODES);
    int s = 0;
    for (int i = lo + t; i < hi; i += SCAN_T) s += deg[i];
    #pragma unroll
    for (int m = 1; m < 64; m <<= 1) s += __shfl_xor(s, m);
    __shared__ int ws[SCAN_T / 64];
    if ((t & 63) == 0) ws[t >> 6] = s;
    __syncthreads();
    if (t == 0) {
        int tot = 0;
        #pragma unroll
        for (int w = 0; w < SCAN_T / 64; ++w) tot += ws[w];
        bsum[b] = tot;
    }
}

__global__ __launch_bounds__(SCAN_BLOCKS) void offset_scan_kernel(
        const int* __restrict__ bsum, int* __restrict__ boff) {
    __shared__ int tmp[SCAN_BLOCKS];
    int t = threadIdx.x;
    int v = bsum[t];
    tmp[t] = v;
    __syncthreads();
    int val = v;
    for (int off = 1; off < SCAN_BLOCKS; off <<= 1) {
        int o = (t >= off) ? tmp[t - off] : 0;
        __syncthreads();
        val += o;
        tmp[t] = val;
        __syncthreads();
    }
    boff[t] = val - v;    // exclusive
}

__global__ __launch_bounds__(SCAN_T) void row_ptr_kernel(
        const int* __restrict__ deg, const int* __restrict__ boff,
        int* __restrict__ row_ptr, int* __restrict__ fill) {
    int b = blockIdx.x, t = threadIdx.x;
    int lo = b * SCAN_CH, hi = min(lo + SCAN_CH, N_NODES);
    __shared__ int tmp[SCAN_T];
    __shared__ int carry;
    if (t == 0) carry = boff[b];
    __syncthreads();
    for (int base = lo; base < hi; base += SCAN_T) {
        int i = base + t;
        int v = (i < hi) ? deg[i] : 0;
        tmp[t] = v;
        __syncthreads();
        int val = v;
        for (int off = 1; off < SCAN_T; off <<= 1) {
            int o = (t >= off) ? tmp[t - off] : 0;
            __syncthreads();
            val += o;
            tmp[t] = val;
            __syncthreads();
        }
        int excl = val - v + carry;
        if (i < hi) { row_ptr[i] = excl; fill[i] = excl; }
        __syncthreads();
        if (t == SCAN_T - 1) carry = carry + val;
        __syncthreads();
    }
    if (b == SCAN_BLOCKS - 1 && t == 0) row_ptr[N_NODES] = carry;  // == E
}

__global__ __launch_bounds__(256) void scatter_kernel(
        const int* __restrict__ ei, int* __restrict__ fill,
        int* __restrict__ col) {
    int e = blockIdx.x * 256 + threadIdx.x;
    if (e < E_EDGES) {
        int d = ei[E_EDGES + e];
        int p = atomicAdd(&fill[d], 1);
        col[p] = ei[e];
    }
}

// ---------------------------------------------------------------------------
// Fused GAT aggregation over CSR: one wave per dst node, no atomics.
// Lane l owns channels (2l, 2l+1) of one head (l>>3): one exp per edge per
// lane, one half2 gather per edge per lane (256 B contiguous per wave).
// FUSE=true additionally computes both regression/classifier heads in-wave
// and writes the final outputs (no h round-trip through HBM).
// ---------------------------------------------------------------------------
template<bool FUSE>
__global__ __launch_bounds__(256) void gat_aggr_csr_kernel(
        const int* __restrict__ row_ptr, const int* __restrict__ col,
        const float* __restrict__ a_src, const float* __restrict__ a_dst,
        const __half* __restrict__ g, const float* __restrict__ bias,
        float* __restrict__ out,
        const float* __restrict__ Wy1, const float* __restrict__ by1,
        const float* __restrict__ Wy0, const float* __restrict__ by0,
        const float* __restrict__ Wc1, const float* __restrict__ bc1,
        const float* __restrict__ Wc2, const float* __restrict__ bc2) {
    int wv = threadIdx.x >> 6, lane = threadIdx.x & 63;
    int d = blockIdx.x * 4 + wv;
    if (d >= N_NODES) return;
    int hh = lane >> 3;                  // head 0..7
    const __half2* g2 = (const __half2*)g;
    float ad = a_dst[d * 8 + hh];
    float acc0, acc1, den;
    {   // self loop (s = d)
        float l0 = a_src[d * 8 + hh] + ad;
        l0 = (l0 > 0.f) ? l0 : NEG_SLOPE * l0;
        float w = __expf(l0);
        float2 gv = __half22float2(g2[(size_t)d * 64 + lane]);
        acc0 = w * gv.x; acc1 = w * gv.y; den = w;
    }
    int i = row_ptr[d], end = row_ptr[d + 1];
    for (; i + 2 <= end; i += 2) {
        int sA = col[i], sB = col[i + 1];
        float lA = a_src[sA * 8 + hh] + ad;
        float lB = a_src[sB * 8 + hh] + ad;
        lA = (lA > 0.f) ? lA : NEG_SLOPE * lA;
        lB = (lB > 0.f) ? lB : NEG_SLOPE * lB;
        float wA = __expf(lA), wB = __expf(lB);
        float2 gA = __half22float2(g2[(size_t)sA * 64 + lane]);
        float2 gB = __half22float2(g2[(size_t)sB * 64 + lane]);
        acc0 += wA * gA.x + wB * gB.x;
        acc1 += wA * gA.y + wB * gB.y;
        den  += wA + wB;
    }
    if (i < end) {
        int s = col[i];
        float l0 = a_src[s * 8 + hh] + ad;
        l0 = (l0 > 0.f) ? l0 : NEG_SLOPE * l0;
        float w = __expf(l0);
        float2 gv = __half22float2(g2[(size_t)s * 64 + lane]);
        acc0 += w * gv.x; acc1 += w * gv.y; den += w;
    }
    float inv = 1.f / (den + 1e-16f);
    int c0 = lane << 1;
    float hA = acc0 * inv + bias[c0];
    float hB = acc1 * inv + bias[c0 + 1];
    if (!FUSE) {
        *(float2*)&out[(size_t)d * HD + c0] = make_float2(hA, hB);
    } else {
        float p = hA * (Wy1[c0] - Wy0[c0]) + hB * (Wy1[c0 + 1] - Wy0[c0 + 1]);
        #pragma unroll
        for (int m = 1; m < 64; m <<= 1) p += __shfl_xor(p, m);
        float acc2 = 0.f;
        #pragma unroll
        for (int j = 0; j < D_DIM; ++j) {
            float q = hA * Wc1[c0 * D_DIM + j] + hB * Wc1[(c0 + 1) * D_DIM + j];
            #pragma unroll
            for (int m = 1; m < 64; m <<= 1) q += __shfl_xor(q, m);
            float z = q + bc1[j];
            z = (z > 0.f) ? z : 0.f;
            acc2 += z * Wc2[j];
        }
        if (lane == 0) {
            out[d] = p + by1[0] - by0[0];
            out[N_NODES + d] = 1.f / (1.f + __expf(-(acc2 + bc2[0])));
        }
    }
}

// ---------------------------------------------------------------------------
extern "C" void kernel_launch(void* const* d_in, const int* in_sizes, int n_in,
                              void* d_out, int out_size, void* d_ws, size_t ws_size,
                              hipStream_t stream) {
    const float* x     = (const float*)d_in[0];
    const int*   ei    = (const int*)  d_in[1];
    const float* W_emb = (const float*)d_in[2];
    const float* b_emb = (const float*)d_in[3];
    const float* W0    = (const float*)d_in[4];
    const float* as0   = (const float*)d_in[5];
    const float* ad0   = (const float*)d_in[6];
    const float* b0    = (const float*)d_in[7];
    const float* W1    = (const float*)d_in[8];
    const float* as1   = (const float*)d_in[9];
    const float* ad1   = (const float*)d_in[10];
    const float* b1    = (const float*)d_in[11];
    const float* Wy1   = (const float*)d_in[12];
    const float* by1   = (const float*)d_in[13];
    const float* Wy0   = (const float*)d_in[14];
    const float* by0   = (const float*)d_in[15];
    const float* Wc1   = (const float*)d_in[16];
    const float* bc1   = (const float*)d_in[17];
    const float* Wc2   = (const float*)d_in[18];
    const float* bc2   = (const float*)d_in[19];
    float* out = (float*)d_out;

    float* ws    = (float*)d_ws;
    __half* gH   = (__half*)ws;                          // N*128 halves (25.6MB)
    float* bufH  = (float*)(ws + (size_t)N_NODES * HD / 2 + 64);  // N*128 f32
    float* h0    = bufH + (size_t)N_NODES * HD;          // N*16
    float* a_s   = h0   + (size_t)N_NODES * D_DIM;       // N*8
    float* a_d   = a_s  + (size_t)N_NODES * H_HEADS;     // N*8
    int*   deg     = (int*)(a_d + (size_t)N_NODES * H_HEADS);  // N
    int*   fill    = deg + N_NODES;                            // N
    int*   row_ptr = fill + N_NODES;                           // N+1
    int*   bsum    = row_ptr + (N_NODES + 1);                  // 256
    int*   boff    = bsum + SCAN_BLOCKS;                       // 256
    int*   col     = boff + SCAN_BLOCKS;                       // E

    int edgeBlocks = (E_EDGES + 255) / 256;
    int aggrBlocks = (N_NODES + 3) / 4;

    // ----- CSR build (once; reused by both layers) -----
    hipMemsetAsync(deg, 0, (size_t)N_NODES * sizeof(int), stream);
    hipLaunchKernelGGL(hist_kernel, dim3(edgeBlocks), dim3(256), 0, stream, ei, deg);
    hipLaunchKernelGGL(block_sum_kernel, dim3(SCAN_BLOCKS), dim3(SCAN_T), 0, stream,
                       deg, bsum);
    hipLaunchKernelGGL(offset_scan_kernel, dim3(1), dim3(SCAN_BLOCKS), 0, stream,
                       bsum, boff);
    hipLaunchKernelGGL(row_ptr_kernel, dim3(SCAN_BLOCKS), dim3(SCAN_T), 0, stream,
                       deg, boff, row_ptr, fill);
    hipLaunchKernelGGL(scatter_kernel, dim3(edgeBlocks), dim3(256), 0, stream,
                       ei, fill, col);

    // ----- Embedding -----
    hipLaunchKernelGGL(embed_kernel, dim3(512), dim3(256), 0, stream,
                       x, W_emb, b_emb, h0);

    // ----- GAT layer 0 (K = 16) -----
    hipLaunchKernelGGL(transform_gemm_kernel<16>, dim3(2048), dim3(256), 0, stream,
                       h0, W0, as0, ad0, gH, a_s, a_d);
    hipLaunchKernelGGL(gat_aggr_csr_kernel<false>, dim3(aggrBlocks), dim3(256), 0, stream,
                       row_ptr, col, a_s, a_d, gH, b0, bufH,
                       (const float*)nullptr, (const float*)nullptr,
                       (const float*)nullptr, (const float*)nullptr,
                       (const float*)nullptr, (const float*)nullptr,
                       (const float*)nullptr, (const float*)nullptr);

    // ----- GAT layer 1 (K = 128) + fused heads -----
    hipLaunchKernelGGL(transform_gemm_kernel<128>, dim3(1024), dim3(256), 0, stream,
                       bufH, W1, as1, ad1, gH, a_s, a_d);
    hipLaunchKernelGGL(gat_aggr_csr_kernel<true>, dim3(aggrBlocks), dim3(256), 0, stream,
                       row_ptr, col, a_s, a_d, gH, b1, out,
                       Wy1, by1, Wy0, by0, Wc1, bc1, Wc2, bc2);
}

// Round 6
// 580.633 us; speedup vs baseline: 3.3671x; 1.0838x over previous
//
#include <hip/hip_runtime.h>
#include <hip/hip_fp16.h>
#include <math.h>

#define N_NODES 100000
#define E_EDGES 1600000
#define F_IN 128
#define D_DIM 16
#define H_HEADS 8
#define HD 128
#define NEG_SLOPE 0.2f

#define SCAN_BLOCKS 256
#define SCAN_T 256
#define SCAN_CH ((N_NODES + SCAN_BLOCKS - 1) / SCAN_BLOCKS)   // 391

#define NTILES ((N_NODES + 63) / 64)        // 1563 node-tiles of 64

// ---------------------------------------------------------------------------
// Embedding: h0[n, 0..15] = x[n, :] @ W_emb + b_emb
// ---------------------------------------------------------------------------
__global__ __launch_bounds__(256) void embed_kernel(
        const float* __restrict__ x, const float* __restrict__ W,
        const float* __restrict__ b, float* __restrict__ h0) {
    __shared__ float Ws[F_IN * D_DIM];   // 8 KB
    __shared__ float bs[D_DIM];
    __shared__ float xs[16][F_IN + 1];
    int t = threadIdx.x;
    for (int i = t; i < F_IN * D_DIM; i += 256) Ws[i] = W[i];
    if (t < D_DIM) bs[t] = b[t];
    __syncthreads();
    for (int base = blockIdx.x * 16; base < N_NODES; base += gridDim.x * 16) {
        int cnt = min(16, N_NODES - base);
        __syncthreads();
        for (int i = t; i < cnt * F_IN; i += 256) {
            int nn = i >> 7, k = i & 127;
            xs[nn][k] = x[(size_t)(base + nn) * F_IN + k];
        }
        __syncthreads();
        int nn = t >> 4, c = t & 15;
        if (nn < cnt) {
            float a0 = 0.f, a1 = 0.f, a2 = 0.f, a3 = 0.f;
            #pragma unroll
            for (int k = 0; k < F_IN; k += 4) {
                a0 += xs[nn][k + 0] * Ws[(k + 0) * D_DIM + c];
                a1 += xs[nn][k + 1] * Ws[(k + 1) * D_DIM + c];
                a2 += xs[nn][k + 2] * Ws[(k + 2) * D_DIM + c];
                a3 += xs[nn][k + 3] * Ws[(k + 3) * D_DIM + c];
            }
            h0[(size_t)(base + nn) * D_DIM + c] = (a0 + a1) + (a2 + a3) + bs[c];
        }
    }
}

// ---------------------------------------------------------------------------
// Node transform as register-tiled GEMM: [N,K] @ [K,128] -> g (fp16), + attn
// dots (fp32, computed from fp32 accumulators before rounding).
// ---------------------------------------------------------------------------
template<int K>
__global__ __launch_bounds__(256) void transform_gemm_kernel(
        const float* __restrict__ h, const float* __restrict__ W,
        const float* __restrict__ att_s, const float* __restrict__ att_d,
        __half* __restrict__ g, float* __restrict__ a_src, float* __restrict__ a_dst) {
    __shared__ float Ws[K][64];          // K=128: 32 KB, K=16: 4 KB
    __shared__ float hs[64][K + 4];      // pad +4 floats: break row-bank stack
    int t = threadIdx.x;
    int cq = t & 15;                     // channel quad within half (0..15)
    int nq = t >> 4;                     // node quad (0..15)
    constexpr int KSH = (K == 128) ? 7 : 4;

    for (int item = blockIdx.x; item < NTILES * 2; item += gridDim.x) {
        int tile = item >> 1;
        int coff = (item & 1) << 6;                 // 0 or 64
        int nbase = tile << 6;
        __syncthreads();                            // protect prev iter reads
        // stage W column-half: K x 64
        for (int i = t; i < K * 64; i += 256)
            Ws[i >> 6][i & 63] = W[(size_t)(i >> 6) * HD + coff + (i & 63)];
        // stage 64 h rows (clamped in tail tile)
        for (int i = t; i < (K << 6); i += 256) {
            int r = i >> KSH, k = i & (K - 1);
            int n = nbase + r; if (n >= N_NODES) n = N_NODES - 1;
            hs[r][k] = h[(size_t)n * K + k];
        }
        __syncthreads();

        float acc[4][4] = {{0.f}};
        #pragma unroll 2
        for (int k = 0; k < K; k += 4) {
            float4 w0 = *(const float4*)&Ws[k + 0][cq << 2];
            float4 w1 = *(const float4*)&Ws[k + 1][cq << 2];
            float4 w2 = *(const float4*)&Ws[k + 2][cq << 2];
            float4 w3 = *(const float4*)&Ws[k + 3][cq << 2];
            #pragma unroll
            for (int j = 0; j < 4; ++j) {
                float4 hv = *(const float4*)&hs[(nq << 2) + j][k];
                acc[j][0] += hv.x * w0.x + hv.y * w1.x + hv.z * w2.x + hv.w * w3.x;
                acc[j][1] += hv.x * w0.y + hv.y * w1.y + hv.z * w2.y + hv.w * w3.y;
                acc[j][2] += hv.x * w0.z + hv.y * w1.z + hv.z * w2.z + hv.w * w3.z;
                acc[j][3] += hv.x * w0.w + hv.y * w1.w + hv.z * w2.w + hv.w * w3.w;
            }
        }

        int c0 = coff + (cq << 2);
        float as0 = att_s[c0], as1 = att_s[c0 + 1], as2 = att_s[c0 + 2], as3 = att_s[c0 + 3];
        float ad0 = att_d[c0], ad1 = att_d[c0 + 1], ad2 = att_d[c0 + 2], ad3 = att_d[c0 + 3];
        int head = c0 >> 4;
        #pragma unroll
        for (int j = 0; j < 4; ++j) {
            int n = nbase + (nq << 2) + j;
            float ps = acc[j][0] * as0 + acc[j][1] * as1 + acc[j][2] * as2 + acc[j][3] * as3;
            float pd = acc[j][0] * ad0 + acc[j][1] * ad1 + acc[j][2] * ad2 + acc[j][3] * ad3;
            ps += __shfl_xor(ps, 1); ps += __shfl_xor(ps, 2);
            pd += __shfl_xor(pd, 1); pd += __shfl_xor(pd, 2);
            if (n < N_NODES) {
                union { __half2 h2[2]; uint2 u; } pk;
                pk.h2[0] = __floats2half2_rn(acc[j][0], acc[j][1]);
                pk.h2[1] = __floats2half2_rn(acc[j][2], acc[j][3]);
                *(uint2*)&g[(size_t)n * HD + c0] = pk.u;
                if ((cq & 3) == 0) {
                    a_src[(size_t)n * H_HEADS + head] = ps;
                    a_dst[(size_t)n * H_HEADS + head] = pd;
                }
            }
        }
    }
}

// ---------------------------------------------------------------------------
// CSR build: histogram -> 3-phase multi-block scan -> scatter.
// ---------------------------------------------------------------------------
__global__ __launch_bounds__(256) void hist_kernel(
        const int* __restrict__ ei, int* __restrict__ deg) {
    int e = blockIdx.x * 256 + threadIdx.x;
    if (e < E_EDGES) atomicAdd(&deg[ei[E_EDGES + e]], 1);
}

__global__ __launch_bounds__(SCAN_T) void block_sum_kernel(
        const int* __restrict__ deg, int* __restrict__ bsum) {
    int b = blockIdx.x, t = threadIdx.x;
    int lo = b * SCAN_CH, hi = min(lo + SCAN_CH, N_NODES);
    int s = 0;
    for (int i = lo + t; i < hi; i += SCAN_T) s += deg[i];
    #pragma unroll
    for (int m = 1; m < 64; m <<= 1) s += __shfl_xor(s, m);
    __shared__ int ws[SCAN_T / 64];
    if ((t & 63) == 0) ws[t >> 6] = s;
    __syncthreads();
    if (t == 0) {
        int tot = 0;
        #pragma unroll
        for (int w = 0; w < SCAN_T / 64; ++w) tot += ws[w];
        bsum[b] = tot;
    }
}

__global__ __launch_bounds__(SCAN_BLOCKS) void offset_scan_kernel(
        const int* __restrict__ bsum, int* __restrict__ boff) {
    __shared__ int tmp[SCAN_BLOCKS];
    int t = threadIdx.x;
    int v = bsum[t];
    tmp[t] = v;
    __syncthreads();
    int val = v;
    for (int off = 1; off < SCAN_BLOCKS; off <<= 1) {
        int o = (t >= off) ? tmp[t - off] : 0;
        __syncthreads();
        val += o;
        tmp[t] = val;
        __syncthreads();
    }
    boff[t] = val - v;    // exclusive
}

__global__ __launch_bounds__(SCAN_T) void row_ptr_kernel(
        const int* __restrict__ deg, const int* __restrict__ boff,
        int* __restrict__ row_ptr, int* __restrict__ fill) {
    int b = blockIdx.x, t = threadIdx.x;
    int lo = b * SCAN_CH, hi = min(lo + SCAN_CH, N_NODES);
    __shared__ int tmp[SCAN_T];
    __shared__ int carry;
    if (t == 0) carry = boff[b];
    __syncthreads();
    for (int base = lo; base < hi; base += SCAN_T) {
        int i = base + t;
        int v = (i < hi) ? deg[i] : 0;
        tmp[t] = v;
        __syncthreads();
        int val = v;
        for (int off = 1; off < SCAN_T; off <<= 1) {
            int o = (t >= off) ? tmp[t - off] : 0;
            __syncthreads();
            val += o;
            tmp[t] = val;
            __syncthreads();
        }
        int excl = val - v + carry;
        if (i < hi) { row_ptr[i] = excl; fill[i] = excl; }
        __syncthreads();
        if (t == SCAN_T - 1) carry = carry + val;
        __syncthreads();
    }
    if (b == SCAN_BLOCKS - 1 && t == 0) row_ptr[N_NODES] = carry;  // == E
}

__global__ __launch_bounds__(256) void scatter_kernel(
        const int* __restrict__ ei, int* __restrict__ fill,
        int* __restrict__ col) {
    int e = blockIdx.x * 256 + threadIdx.x;
    if (e < E_EDGES) {
        int d = ei[E_EDGES + e];
        int p = atomicAdd(&fill[d], 1);
        col[p] = ei[e];
    }
}

// ---------------------------------------------------------------------------
// Fused GAT aggregation over CSR: one wave per dst node, no atomics.
// Lane l owns channels (2l, 2l+1) of head l>>3. Edge loop unrolled x4:
// 4 independent col loads -> 4 a_src gathers -> 4 g-row gathers in flight
// per iteration (latency hiding; round-5 unroll-2 was latency-bound).
// ---------------------------------------------------------------------------
template<bool FUSE>
__global__ __launch_bounds__(256) void gat_aggr_csr_kernel(
        const int* __restrict__ row_ptr, const int* __restrict__ col,
        const float* __restrict__ a_src, const float* __restrict__ a_dst,
        const __half* __restrict__ g, const float* __restrict__ bias,
        float* __restrict__ out,
        const float* __restrict__ Wy1, const float* __restrict__ by1,
        const float* __restrict__ Wy0, const float* __restrict__ by0,
        const float* __restrict__ Wc1, const float* __restrict__ bc1,
        const float* __restrict__ Wc2, const float* __restrict__ bc2) {
    int wv = threadIdx.x >> 6, lane = threadIdx.x & 63;
    int d = blockIdx.x * 4 + wv;
    if (d >= N_NODES) return;
    int hh = lane >> 3;                  // head 0..7
    const __half2* gp = (const __half2*)g;
    float ad = a_dst[d * 8 + hh];
    float acc0, acc1, den;
    {   // self loop (s = d)
        float l0 = a_src[d * 8 + hh] + ad;
        l0 = (l0 > 0.f) ? l0 : NEG_SLOPE * l0;
        float w = __expf(l0);
        float2 gv = __half22float2(gp[(size_t)d * 64 + lane]);
        acc0 = w * gv.x; acc1 = w * gv.y; den = w;
    }
    int i = row_ptr[d], end = row_ptr[d + 1];
    for (; i + 4 <= end; i += 4) {
        int s0 = col[i], s1 = col[i + 1], s2 = col[i + 2], s3 = col[i + 3];
        float l0 = a_src[s0 * 8 + hh] + ad;
        float l1 = a_src[s1 * 8 + hh] + ad;
        float l2 = a_src[s2 * 8 + hh] + ad;
        float l3 = a_src[s3 * 8 + hh] + ad;
        float2 g0 = __half22float2(gp[(size_t)s0 * 64 + lane]);
        float2 g1 = __half22float2(gp[(size_t)s1 * 64 + lane]);
        float2 g2 = __half22float2(gp[(size_t)s2 * 64 + lane]);
        float2 g3 = __half22float2(gp[(size_t)s3 * 64 + lane]);
        l0 = (l0 > 0.f) ? l0 : NEG_SLOPE * l0;
        l1 = (l1 > 0.f) ? l1 : NEG_SLOPE * l1;
        l2 = (l2 > 0.f) ? l2 : NEG_SLOPE * l2;
        l3 = (l3 > 0.f) ? l3 : NEG_SLOPE * l3;
        float w0 = __expf(l0), w1 = __expf(l1);
        float w2 = __expf(l2), w3 = __expf(l3);
        acc0 += (w0 * g0.x + w1 * g1.x) + (w2 * g2.x + w3 * g3.x);
        acc1 += (w0 * g0.y + w1 * g1.y) + (w2 * g2.y + w3 * g3.y);
        den  += (w0 + w1) + (w2 + w3);
    }
    for (; i < end; ++i) {
        int s = col[i];
        float l0 = a_src[s * 8 + hh] + ad;
        l0 = (l0 > 0.f) ? l0 : NEG_SLOPE * l0;
        float w = __expf(l0);
        float2 gv = __half22float2(gp[(size_t)s * 64 + lane]);
        acc0 += w * gv.x; acc1 += w * gv.y; den += w;
    }
    float inv = 1.f / (den + 1e-16f);
    int c0 = lane << 1;
    float hA = acc0 * inv + bias[c0];
    float hB = acc1 * inv + bias[c0 + 1];
    if (!FUSE) {
        *(float2*)&out[(size_t)d * HD + c0] = make_float2(hA, hB);
    } else {
        float p = hA * (Wy1[c0] - Wy0[c0]) + hB * (Wy1[c0 + 1] - Wy0[c0 + 1]);
        #pragma unroll
        for (int m = 1; m < 64; m <<= 1) p += __shfl_xor(p, m);
        float acc2 = 0.f;
        #pragma unroll
        for (int j = 0; j < D_DIM; ++j) {
            float q = hA * Wc1[c0 * D_DIM + j] + hB * Wc1[(c0 + 1) * D_DIM + j];
            #pragma unroll
            for (int m = 1; m < 64; m <<= 1) q += __shfl_xor(q, m);
            float z = q + bc1[j];
            z = (z > 0.f) ? z : 0.f;
            acc2 += z * Wc2[j];
        }
        if (lane == 0) {
            out[d] = p + by1[0] - by0[0];
            out[N_NODES + d] = 1.f / (1.f + __expf(-(acc2 + bc2[0])));
        }
    }
}

// ---------------------------------------------------------------------------
extern "C" void kernel_launch(void* const* d_in, const int* in_sizes, int n_in,
                              void* d_out, int out_size, void* d_ws, size_t ws_size,
                              hipStream_t stream) {
    const float* x     = (const float*)d_in[0];
    const int*   ei    = (const int*)  d_in[1];
    const float* W_emb = (const float*)d_in[2];
    const float* b_emb = (const float*)d_in[3];
    const float* W0    = (const float*)d_in[4];
    const float* as0   = (const float*)d_in[5];
    const float* ad0   = (const float*)d_in[6];
    const float* b0    = (const float*)d_in[7];
    const float* W1    = (const float*)d_in[8];
    const float* as1   = (const float*)d_in[9];
    const float* ad1   = (const float*)d_in[10];
    const float* b1    = (const float*)d_in[11];
    const float* Wy1   = (const float*)d_in[12];
    const float* by1   = (const float*)d_in[13];
    const float* Wy0   = (const float*)d_in[14];
    const float* by0   = (const float*)d_in[15];
    const float* Wc1   = (const float*)d_in[16];
    const float* bc1   = (const float*)d_in[17];
    const float* Wc2   = (const float*)d_in[18];
    const float* bc2   = (const float*)d_in[19];
    float* out = (float*)d_out;

    float* ws    = (float*)d_ws;
    __half* gH   = (__half*)ws;                          // N*128 halves (25.6MB)
    float* bufH  = (float*)(ws + (size_t)N_NODES * HD / 2 + 64);  // N*128 f32
    float* h0    = bufH + (size_t)N_NODES * HD;          // N*16
    float* a_s   = h0   + (size_t)N_NODES * D_DIM;       // N*8
    float* a_d   = a_s  + (size_t)N_NODES * H_HEADS;     // N*8
    int*   deg     = (int*)(a_d + (size_t)N_NODES * H_HEADS);  // N
    int*   fill    = deg + N_NODES;                            // N
    int*   row_ptr = fill + N_NODES;                           // N+1
    int*   bsum    = row_ptr + (N_NODES + 1);                  // 256
    int*   boff    = bsum + SCAN_BLOCKS;                       // 256
    int*   col     = boff + SCAN_BLOCKS;                       // E

    int edgeBlocks = (E_EDGES + 255) / 256;
    int aggrBlocks = (N_NODES + 3) / 4;

    // ----- CSR build (once; reused by both layers) -----
    hipMemsetAsync(deg, 0, (size_t)N_NODES * sizeof(int), stream);
    hipLaunchKernelGGL(hist_kernel, dim3(edgeBlocks), dim3(256), 0, stream, ei, deg);
    hipLaunchKernelGGL(block_sum_kernel, dim3(SCAN_BLOCKS), dim3(SCAN_T), 0, stream,
                       deg, bsum);
    hipLaunchKernelGGL(offset_scan_kernel, dim3(1), dim3(SCAN_BLOCKS), 0, stream,
                       bsum, boff);
    hipLaunchKernelGGL(row_ptr_kernel, dim3(SCAN_BLOCKS), dim3(SCAN_T), 0, stream,
                       deg, boff, row_ptr, fill);
    hipLaunchKernelGGL(scatter_kernel, dim3(edgeBlocks), dim3(256), 0, stream,
                       ei, fill, col);

    // ----- Embedding -----
    hipLaunchKernelGGL(embed_kernel, dim3(512), dim3(256), 0, stream,
                       x, W_emb, b_emb, h0);

    // ----- GAT layer 0 (K = 16) -----
    hipLaunchKernelGGL(transform_gemm_kernel<16>, dim3(2048), dim3(256), 0, stream,
                       h0, W0, as0, ad0, gH, a_s, a_d);
    hipLaunchKernelGGL(gat_aggr_csr_kernel<false>, dim3(aggrBlocks), dim3(256), 0, stream,
                       row_ptr, col, a_s, a_d, gH, b0, bufH,
                       (const float*)nullptr, (const float*)nullptr,
                       (const float*)nullptr, (const float*)nullptr,
                       (const float*)nullptr, (const float*)nullptr,
                       (const float*)nullptr, (const float*)nullptr);

    // ----- GAT layer 1 (K = 128) + fused heads -----
    hipLaunchKernelGGL(transform_gemm_kernel<128>, dim3(1024), dim3(256), 0, stream,
                       bufH, W1, as1, ad1, gH, a_s, a_d);
    hipLaunchKernelGGL(gat_aggr_csr_kernel<true>, dim3(aggrBlocks), dim3(256), 0, stream,
                       row_ptr, col, a_s, a_d, gH, b1, out,
                       Wy1, by1, Wy0, by0, Wc1, bc1, Wc2, bc2);
}